// Round 7
// baseline (2599.198 us; speedup 1.0000x reference)
//
#include <hip/hip_runtime.h>
#include <hip/hip_bf16.h>

typedef __hip_bfloat16 bf16;

// ---------- dtype-adaptive loads (flags are wave-uniform) ----------
__device__ __forceinline__ float ldf(const void* p, long long i, int f32){
  return f32 ? ((const float*)p)[i] : __bfloat162float(((const bf16*)p)[i]);
}
__device__ __forceinline__ int ldi(const void* p, long long i, int i64){
  return i64 ? (int)((const long long*)p)[i] : ((const int*)p)[i];
}

// ---------- sniff input dtypes once per launch ----------
__global__ void k_sniff(const void* __restrict__ x, const void* __restrict__ eidx,
                        int* __restrict__ flags){
  __shared__ int s_f, s_i;
  if (threadIdx.x == 0){ s_f = 0; s_i = 0; }
  __syncthreads();
  int t = threadIdx.x;
  const unsigned short* u = (const unsigned short*)x;
  int hits = 0;
  for (int k = t; k < 2048; k += 256){
    unsigned short v = u[2*k];
    int e = (v >> 7) & 0xFF;
    if (e == 0xFF || e == 0x00) hits++;
  }
  if (hits) atomicAdd(&s_f, 1);
  const int* ii = (const int*)eidx;
  int nz = 0;
  for (int k = t; k < 1024; k += 256){ if (ii[2*k+1] != 0) nz++; }
  if (nz) atomicAdd(&s_i, 1);
  __syncthreads();
  if (threadIdx.x == 0){
    flags[0] = s_f ? 1 : 0;   // 1 = float32, 0 = bf16
    flags[1] = s_i ? 0 : 1;   // 1 = int64,   0 = int32
  }
}

__global__ void k_zero(int* __restrict__ p, int n){
  int i = blockIdx.x*256 + threadIdx.x;
  if (i < n) p[i] = 0;
}

// ================= binned edge grouping (no per-node sort) =================

__global__ void __launch_bounds__(256) k_bhist(const void* __restrict__ eidx, long long E,
                       const int* __restrict__ flags, int shift, int NB,
                       int* __restrict__ bcnt){
  __shared__ int h[1024];
  int t = threadIdx.x;
  for (int b = t; b < NB; b += 256) h[b] = 0;
  __syncthreads();
  int i64 = flags[1];
  long long e0 = (long long)blockIdx.x*4096;
  long long e1 = e0 + 4096; if (e1 > E) e1 = E;
  for (long long e = e0 + t; e < e1; e += 256){
    int d = ldi(eidx, E + e, i64);
    atomicAdd(&h[d >> shift], 1);
  }
  __syncthreads();
  for (int b = t; b < NB; b += 256) if (h[b]) atomicAdd(&bcnt[b], h[b]);
}

__global__ void __launch_bounds__(256) k_bscan(const int* __restrict__ bcnt, int* __restrict__ bbase,
                       int NB, int E){
  __shared__ int tmp[256];
  int t = threadIdx.x;
  int v0 = (4*t+0 < NB) ? bcnt[4*t+0] : 0;
  int v1 = (4*t+1 < NB) ? bcnt[4*t+1] : 0;
  int v2 = (4*t+2 < NB) ? bcnt[4*t+2] : 0;
  int v3 = (4*t+3 < NB) ? bcnt[4*t+3] : 0;
  int s = v0+v1+v2+v3;
  tmp[t] = s;
  __syncthreads();
  for (int st = 1; st < 256; st <<= 1){
    int add = (t >= st) ? tmp[t-st] : 0;
    __syncthreads();
    tmp[t] += add;
    __syncthreads();
  }
  int run = tmp[t] - s;
  if (4*t+0 < NB){ bbase[4*t+0] = run; run += v0; }
  if (4*t+1 < NB){ bbase[4*t+1] = run; run += v1; }
  if (4*t+2 < NB){ bbase[4*t+2] = run; run += v2; }
  if (4*t+3 < NB){ bbase[4*t+3] = run; run += v3; }
  if (t == 255) bbase[NB] = E;
}

// 2048-edge chunks: LDS counting-sort by bucket, write run-contiguous into csr.
// csr entry: x = (dstLow<<24)|src, y = raw edge weight (float bits).
#define BINCH 2048
__global__ void __launch_bounds__(256) k_bin(const void* __restrict__ eidx, long long E,
                     const void* __restrict__ ew, const int* __restrict__ flags,
                     int shift, int NB, const int* __restrict__ bbase,
                     int* __restrict__ gcur, int2* __restrict__ csr){
  __shared__ int bst[1024];
  __shared__ int bcur[1024];
  __shared__ int gof[1024];
  __shared__ int tmp[256];
  __shared__ int2 ent[BINCH];
  __shared__ unsigned short entb[BINCH];
  int t = threadIdx.x;
  int i64 = flags[1], f32 = flags[0];
  long long e0 = (long long)blockIdx.x*BINCH;
  int cnt = (int)(((E - e0) < BINCH) ? (E - e0) : BINCH);
  int msk = (1 << shift) - 1;
  for (int b = t; b < NB; b += 256) bst[b] = 0;
  __syncthreads();
  for (int i = t; i < cnt; i += 256){
    int d = ldi(eidx, E + e0 + i, i64);
    atomicAdd(&bst[d >> shift], 1);
  }
  __syncthreads();
  int v0 = (4*t+0 < NB) ? bst[4*t+0] : 0;
  int v1 = (4*t+1 < NB) ? bst[4*t+1] : 0;
  int v2 = (4*t+2 < NB) ? bst[4*t+2] : 0;
  int v3 = (4*t+3 < NB) ? bst[4*t+3] : 0;
  int s = v0+v1+v2+v3;
  tmp[t] = s;
  __syncthreads();
  for (int st = 1; st < 256; st <<= 1){
    int add = (t >= st) ? tmp[t-st] : 0;
    __syncthreads();
    tmp[t] += add;
    __syncthreads();
  }
  int run = tmp[t] - s;
  __syncthreads();
  if (4*t+0 < NB){ bst[4*t+0]=run; bcur[4*t+0]=run; if (v0) gof[4*t+0]=atomicAdd(&gcur[4*t+0], v0); run += v0; }
  if (4*t+1 < NB){ bst[4*t+1]=run; bcur[4*t+1]=run; if (v1) gof[4*t+1]=atomicAdd(&gcur[4*t+1], v1); run += v1; }
  if (4*t+2 < NB){ bst[4*t+2]=run; bcur[4*t+2]=run; if (v2) gof[4*t+2]=atomicAdd(&gcur[4*t+2], v2); run += v2; }
  if (4*t+3 < NB){ bst[4*t+3]=run; bcur[4*t+3]=run; if (v3) gof[4*t+3]=atomicAdd(&gcur[4*t+3], v3); run += v3; }
  __syncthreads();
  for (int i = t; i < cnt; i += 256){
    int d  = ldi(eidx, E + e0 + i, i64);
    int sc = ldi(eidx, e0 + i, i64);
    float w = ldf(ew, e0 + i, f32);
    int b = d >> shift;
    int dl = d & msk;
    int pos = atomicAdd(&bcur[b], 1);
    ent[pos]  = make_int2((dl << 24) | sc, __float_as_int(w));
    entb[pos] = (unsigned short)b;
  }
  __syncthreads();
  for (int i = t; i < cnt; i += 256){
    int b = entb[i];
    int gpos = bbase[b] + gof[b] + (i - bst[b]);
    csr[gpos] = ent[i];
  }
}

// per-bucket degree: deg[n] = 1 + sum w over in-edges; dinv = rsqrt(deg)
__global__ void __launch_bounds__(256) k_bdeg(const int2* __restrict__ csr, const int* __restrict__ bbase,
                      int shift, int N, float* __restrict__ dinv){
  __shared__ float wsum[256];
  int b = blockIdx.x, t = threadIdx.x;
  int base = bbase[b], cnt = bbase[b+1] - base;
  wsum[t] = 0.f;
  __syncthreads();
  for (int i = t; i < cnt; i += 256){
    int2 p = csr[base + i];
    atomicAdd(&wsum[((unsigned)p.x) >> 24], __int_as_float(p.y));
  }
  __syncthreads();
  int n = (b << shift) + t;
  if (t < (1 << shift) && n < N){
    float deg = 1.f + wsum[t];
    dinv[n] = (deg > 0.f) ? rsqrtf(fmaxf(deg, 1e-30f)) : 0.f;
  }
}

// ---------- bucket pull: one 128-node bucket per block, LDS accumulation ----------
// zp = dinv*(h W)  (produced by the matmuls). agg[n] = dinv[n]*(zp[n] + sum w*zp[src]).
__global__ void __launch_bounds__(256) k_pullb(const int2* __restrict__ csr, const int* __restrict__ bbase,
                       const float* __restrict__ dinv, const float* __restrict__ zp,
                       float* __restrict__ agg, int N, int shift){
  __shared__ float acc[128*32];
  __shared__ float sdv[128];
  int b = blockIdx.x, t = threadIdx.x;
  int base = bbase[b], cnt = bbase[b+1] - base;
  long long n0 = (long long)b << shift;
  for (int i = t; i < 128*32; i += 256){
    long long n = n0 + (i >> 5);
    acc[i] = (n < N) ? zp[n*32 + (i & 31)] : 0.f;   // self-loop term (weight 1)
  }
  if (t < 128){
    long long n = n0 + t;
    sdv[t] = (n < N) ? dinv[n] : 0.f;
  }
  __syncthreads();
  int wave = t >> 6, l = t & 63, f = l & 31, sub = l >> 5;
  for (int e = wave*2 + sub; e < cnt; e += 8){
    int2 p = csr[base + e];                         // broadcast within 32-lane half
    int dl = ((unsigned)p.x) >> 24;
    int src = p.x & 0xFFFFFF;
    float w = __int_as_float(p.y);
    float hv = zp[(long long)src*32 + f];           // 128B coalesced row gather
    atomicAdd(&acc[dl*32 + f], w * hv);             // 32 distinct banks: conflict-free
  }
  __syncthreads();
  for (int i = t; i < 128*32; i += 256){
    long long n = n0 + (i >> 5);
    if (n < N) agg[n*32 + (i & 31)] = sdv[i >> 5] * acc[i];
  }
}

// ---------- layer-1 matmul: 32 rows/block, 4 outputs/thread; K=128, F=32 ----------
// epilogue: out *= dinv[n] when mul_dinv
__global__ void k_mm1(const void* __restrict__ x, const void* __restrict__ W,
                      const int* __restrict__ flags, const float* __restrict__ dinv,
                      int mul_dinv, float* __restrict__ out, int N){
  __shared__ float Ws[128*32];
  __shared__ float xs[32*128];
  int tid = threadIdx.x;
  int f32 = flags[0];
  for (int i = tid; i < 4096; i += 256) Ws[i] = ldf(W, i, f32);
  int n0 = blockIdx.x*32;
  for (int i = tid; i < 4096; i += 256){
    int r = i >> 7, k = i & 127, n = n0 + r;
    xs[i] = (n < N) ? ldf(x, (long long)n*128 + k, f32) : 0.f;
  }
  __syncthreads();
  int f = tid & 31, r = tid >> 5;
  float a0=0.f, a1=0.f, a2=0.f, a3=0.f;
  for (int k = 0; k < 128; ++k){
    float w = Ws[k*32+f];
    a0 = fmaf(xs[(r    )*128+k], w, a0);
    a1 = fmaf(xs[(r+ 8)*128+k], w, a1);
    a2 = fmaf(xs[(r+16)*128+k], w, a2);
    a3 = fmaf(xs[(r+24)*128+k], w, a3);
  }
  int n;
  n = n0+r;    if (n < N) out[n*32+f] = mul_dinv ? a0*dinv[n] : a0;
  n = n0+r+8;  if (n < N) out[n*32+f] = mul_dinv ? a1*dinv[n] : a1;
  n = n0+r+16; if (n < N) out[n*32+f] = mul_dinv ? a2*dinv[n] : a2;
  n = n0+r+24; if (n < N) out[n*32+f] = mul_dinv ? a3*dinv[n] : a3;
}

// ---------- hidden matmul: 32 rows/block; prev layer's bias+relu fused into input ----------
__global__ void k_mmh(const float* __restrict__ in, const void* __restrict__ bias, int do_relu,
                      const void* __restrict__ W, const int* __restrict__ flags,
                      const float* __restrict__ dinv, int mul_dinv,
                      float* __restrict__ out, int N){
  __shared__ float Ws[32*32];
  __shared__ float xs[32*32];
  int tid = threadIdx.x;
  int f32 = flags[0];
  for (int i = tid; i < 1024; i += 256) Ws[i] = ldf(W, i, f32);
  int n0 = blockIdx.x*32;
  for (int i = tid; i < 1024; i += 256){
    int r = i >> 5, k = i & 31, n = n0 + r;
    float v = 0.f;
    if (n < N){
      v = in[n*32+k] + ldf(bias, k, f32);
      if (do_relu) v = fmaxf(v, 0.f);
    }
    xs[i] = v;
  }
  __syncthreads();
  int f = tid & 31, r = tid >> 5;
  float a0=0.f, a1=0.f, a2=0.f, a3=0.f;
  for (int k = 0; k < 32; ++k){
    float w = Ws[k*32+f];
    a0 = fmaf(xs[(r    )*32+k], w, a0);
    a1 = fmaf(xs[(r+ 8)*32+k], w, a1);
    a2 = fmaf(xs[(r+16)*32+k], w, a2);
    a3 = fmaf(xs[(r+24)*32+k], w, a3);
  }
  int n;
  n = n0+r;    if (n < N) out[n*32+f] = mul_dinv ? a0*dinv[n] : a0;
  n = n0+r+8;  if (n < N) out[n*32+f] = mul_dinv ? a1*dinv[n] : a1;
  n = n0+r+16; if (n < N) out[n*32+f] = mul_dinv ? a2*dinv[n] : a2;
  n = n0+r+24; if (n < N) out[n*32+f] = mul_dinv ? a3*dinv[n] : a3;
}

// ---------- mean pool per graph (batch sorted) ----------
__device__ __forceinline__ int lower_bound_i(const void* __restrict__ a, int n, int v, int i64){
  int lo = 0, hi = n;
  while (lo < hi){ int mid = (lo+hi) >> 1; if (ldi(a, mid, i64) < v) lo = mid+1; else hi = mid; }
  return lo;
}

__global__ void k_pool(const float* __restrict__ agg, const void* __restrict__ b3,
                       const void* __restrict__ batch, const int* __restrict__ flags,
                       float* __restrict__ gpool, int N){
  int f32 = flags[0], i64 = flags[1];
  int g = blockIdx.x;
  int start = lower_bound_i(batch, N, g, i64);
  int end   = lower_bound_i(batch, N, g+1, i64);
  int tid = threadIdx.x;
  int f = tid & 31, r = tid >> 5;
  float acc = 0.f;
  for (int n = start + r; n < end; n += 8) acc += agg[n*32+f];
  __shared__ float red[8][32];
  red[r][f] = acc;
  __syncthreads();
  if (r == 0){
    float s = red[0][f];
    #pragma unroll
    for (int j = 1; j < 8; ++j) s += red[j][f];
    int c = end - start;
    float gv = (c > 0) ? (s / (float)c + ldf(b3, f, f32)) : 0.f;
    gpool[g*32+f] = gv;
  }
}

// ---------- MLP head: 1 block, column-per-thread, 16 row-accumulators (ILP) ----------
__global__ void __launch_bounds__(256, 1) k_mlp(const float* __restrict__ gpool,
                      const void* __restrict__ L1w, const void* __restrict__ L1b,
                      const void* __restrict__ L2w, const void* __restrict__ L2b,
                      const void* __restrict__ L3w, const void* __restrict__ L3b,
                      const void* __restrict__ L4w, const void* __restrict__ L4b,
                      const int* __restrict__ flags, void* __restrict__ out){
  __shared__ float gin[64*32];
  __shared__ float A[64*65];
  __shared__ float B[64*65];
  __shared__ float ws[64*64];
  __shared__ float wb[64];
  int tid = threadIdx.x;
  int f32 = flags[0];
  int j  = tid & 63;
  int i0 = tid >> 6;
  float acc[16];

  for (int i = tid; i < 64*32; i += 256) gin[i] = gpool[i];
  for (int i = tid; i < 2048; i += 256) ws[i] = ldf(L1w, i, f32);
  if (tid < 64) wb[tid] = ldf(L1b, tid, f32);
  __syncthreads();
  #pragma unroll
  for (int r = 0; r < 16; ++r) acc[r] = wb[j];
  for (int k = 0; k < 32; ++k){
    float w = ws[k*64+j];
    #pragma unroll
    for (int r = 0; r < 16; ++r) acc[r] = fmaf(gin[(i0+4*r)*32+k], w, acc[r]);
  }
  #pragma unroll
  for (int r = 0; r < 16; ++r) A[(i0+4*r)*65+j] = fmaxf(acc[r], 0.f);
  __syncthreads();
  for (int i = tid; i < 4096; i += 256) ws[i] = ldf(L2w, i, f32);
  if (tid < 64) wb[tid] = ldf(L2b, tid, f32);
  __syncthreads();
  #pragma unroll
  for (int r = 0; r < 16; ++r) acc[r] = wb[j];
  for (int k = 0; k < 64; ++k){
    float w = ws[k*64+j];
    #pragma unroll
    for (int r = 0; r < 16; ++r) acc[r] = fmaf(A[(i0+4*r)*65+k], w, acc[r]);
  }
  #pragma unroll
  for (int r = 0; r < 16; ++r) B[(i0+4*r)*65+j] = fmaxf(acc[r], 0.f);
  __syncthreads();
  for (int i = tid; i < 4096; i += 256) ws[i] = ldf(L3w, i, f32);
  if (tid < 64) wb[tid] = ldf(L3b, tid, f32);
  __syncthreads();
  #pragma unroll
  for (int r = 0; r < 16; ++r) acc[r] = wb[j];
  for (int k = 0; k < 64; ++k){
    float w = ws[k*64+j];
    #pragma unroll
    for (int r = 0; r < 16; ++r) acc[r] = fmaf(B[(i0+4*r)*65+k], w, acc[r]);
  }
  #pragma unroll
  for (int r = 0; r < 16; ++r) A[(i0+4*r)*65+j] = fmaxf(acc[r], 0.f);
  __syncthreads();
  for (int i = tid; i < 640; i += 256) ws[i] = ldf(L4w, i, f32);
  if (tid < 10) wb[tid] = ldf(L4b, tid, f32);
  __syncthreads();
  if (tid < 64){
    int row = tid;
    float a10[10];
    #pragma unroll
    for (int c = 0; c < 10; ++c) a10[c] = wb[c];
    for (int k = 0; k < 64; ++k){
      float av = A[row*65+k];
      #pragma unroll
      for (int c = 0; c < 10; ++c) a10[c] = fmaf(av, ws[k*10+c], a10[c]);
    }
    #pragma unroll
    for (int c = 0; c < 10; ++c){
      if (f32) ((float*)out)[row*10+c] = a10[c];
      else     ((bf16*)out)[row*10+c]  = __float2bfloat16(a10[c]);
    }
  }
}

// ---------- fallback (atomic-scatter path, small ws) ----------
__global__ void k_init_deg(float* __restrict__ deg, int N){
  int i = blockIdx.x*256 + threadIdx.x;
  if (i < N) deg[i] = 1.0f;
}
__global__ void k_deg_accum(const void* __restrict__ eidx, long long E,
                            const void* __restrict__ w, const int* __restrict__ flags,
                            float* __restrict__ deg){
  long long e = (long long)blockIdx.x*256 + threadIdx.x;
  if (e < E){
    int f32 = flags[0], i64 = flags[1];
    atomicAdd(&deg[ldi(eidx, E + e, i64)], ldf(w, e, f32));
  }
}
__global__ void k_dinv(float* __restrict__ deg, int N){
  int i = blockIdx.x*256 + threadIdx.x;
  if (i < N){
    float d = deg[i];
    deg[i] = (d > 0.f) ? rsqrtf(fmaxf(d, 1e-30f)) : 0.f;
  }
}
__global__ void k_norm(const void* __restrict__ eidx, long long E,
                       const void* __restrict__ w, const float* __restrict__ dinv,
                       const int* __restrict__ flags, float* __restrict__ nrm){
  long long e = (long long)blockIdx.x*256 + threadIdx.x;
  if (e < E){
    int f32 = flags[0], i64 = flags[1];
    int s = ldi(eidx, e, i64), d = ldi(eidx, E + e, i64);
    nrm[e] = dinv[s] * ldf(w, e, f32) * dinv[d];
  }
}
__global__ void k_selfloop(const float* __restrict__ hlin, const float* __restrict__ dinv,
                           float* __restrict__ agg, int N){
  int idx = blockIdx.x*256 + threadIdx.x;
  if (idx < N*32){
    int n = idx >> 5;
    float di = dinv[n];
    agg[idx] = di*di*hlin[idx];
  }
}
__global__ void k_scatter(const void* __restrict__ eidx, long long E,
                          const float* __restrict__ nrm, const int* __restrict__ flags,
                          const float* __restrict__ hlin, float* __restrict__ agg){
  long long idx = (long long)blockIdx.x*256 + threadIdx.x;
  if (idx < E*32){
    int i64 = flags[1];
    long long e = idx >> 5;
    int f = (int)(idx & 31);
    int s = ldi(eidx, e, i64), d = ldi(eidx, E + e, i64);
    atomicAdd(&agg[(long long)d*32 + f], nrm[e] * hlin[(long long)s*32 + f]);
  }
}

extern "C" void kernel_launch(void* const* d_in, const int* in_sizes, int n_in,
                              void* d_out, int out_size, void* d_ws, size_t ws_size,
                              hipStream_t stream){
  const void* x   = d_in[0];
  const void* ew  = d_in[1];
  const void* W1  = d_in[2];
  const void* b1  = d_in[3];
  const void* W2  = d_in[4];
  const void* b2  = d_in[5];
  const void* W3  = d_in[6];
  const void* b3  = d_in[7];
  const void* L1w = d_in[8];  const void* L1b = d_in[9];
  const void* L2w = d_in[10]; const void* L2b = d_in[11];
  const void* L3w = d_in[12]; const void* L3b = d_in[13];
  const void* L4w = d_in[14]; const void* L4b = d_in[15];
  const void* eidx  = d_in[16];
  const void* batch = d_in[17];
  const long long E = in_sizes[1];
  const int N = in_sizes[17];

  dim3 b(256);
  int gN   = (N + 255)/256;
  int gE   = (int)((E + 255)/256);
  int gMM  = (N + 31)/32;
  int gBH  = (int)((E + 4095)/4096);
  int gBN  = (int)((E + BINCH - 1)/BINCH);

  const int shift = 7;                       // 128-node buckets (pullb LDS layout)
  int NB = (N + 127) >> 7;

  auto AL = [](size_t v){ return (v + 255) & ~(size_t)255; };

  char* base = (char*)d_ws;
  size_t off = 0;
  size_t o_flags = off; off += AL(64*4);
  size_t o_dinv  = off; off += AL((size_t)N*4);
  size_t o_bbase = off; off += AL((size_t)(NB+1)*4);
  size_t o_bcnt  = off; off += AL((size_t)NB*4) + AL((size_t)NB*4);   // bcnt + gcur
  size_t o_csr   = off; off += AL((size_t)E*8);
  size_t o_bufA  = off; off += AL((size_t)N*128);
  size_t o_bufB  = off; off += AL((size_t)N*128);
  size_t o_gp    = off; off += AL(2048*4);
  size_t needed  = off;

  if (ws_size >= needed && NB <= 1024 && N < (1<<24)){
    int*   flags  = (int*)(base + o_flags);
    float* dinv   = (float*)(base + o_dinv);
    int*   bbase  = (int*)(base + o_bbase);
    int*   bcnt   = (int*)(base + o_bcnt);
    int*   gcur   = (int*)(base + o_bcnt + AL((size_t)NB*4));
    int2*  csr    = (int2*)(base + o_csr);
    float* bufA   = (float*)(base + o_bufA);
    float* bufB   = (float*)(base + o_bufB);
    float* gpool  = (float*)(base + o_gp);

    k_sniff<<<1,   b, 0, stream>>>(x, eidx, flags);
    k_zero <<<(int)((AL((size_t)NB*4)/4 + NB + 255)/256), b, 0, stream>>>(bcnt, (int)(AL((size_t)NB*4)/4 + NB));
    k_bhist<<<gBH, b, 0, stream>>>(eidx, E, flags, shift, NB, bcnt);
    k_bscan<<<1,   b, 0, stream>>>(bcnt, bbase, NB, (int)E);
    k_bin  <<<gBN, b, 0, stream>>>(eidx, E, ew, flags, shift, NB, bbase, gcur, csr);
    k_bdeg <<<NB,  b, 0, stream>>>(csr, bbase, shift, N, dinv);
    // layer 1
    k_mm1  <<<gMM, b, 0, stream>>>(x, W1, flags, dinv, 1, bufA, N);
    k_pullb<<<NB,  b, 0, stream>>>(csr, bbase, dinv, bufA, bufB, N, shift);
    // layer 2
    k_mmh  <<<gMM, b, 0, stream>>>(bufB, b1, 1, W2, flags, dinv, 1, bufA, N);
    k_pullb<<<NB,  b, 0, stream>>>(csr, bbase, dinv, bufA, bufB, N, shift);
    // layer 3
    k_mmh  <<<gMM, b, 0, stream>>>(bufB, b2, 1, W3, flags, dinv, 1, bufA, N);
    k_pullb<<<NB,  b, 0, stream>>>(csr, bbase, dinv, bufA, bufB, N, shift);
    // head
    k_pool<<<64, b, 0, stream>>>(bufB, b3, batch, flags, gpool, N);
    k_mlp <<<1,  b, 0, stream>>>(gpool, L1w, L1b, L2w, L2b, L3w, L3b, L4w, L4b, flags, d_out);
    return;
  }

  // ---- fallback: atomic-scatter path ----
  {
    float* wf    = (float*)d_ws;
    int*   flags = (int*)d_ws;
    size_t Npad  = ((size_t)N + 255) & ~(size_t)255;
    float* dinv  = wf + 64;
    float* nrm   = dinv + Npad;
    float* bufA  = nrm + E;
    float* bufB  = bufA + (size_t)N*32;
    float* gpool = bufB + (size_t)N*32;
    int gN32 = (N*32 + 255)/256;
    int gE32 = (int)((E*32 + 255)/256);

    k_sniff    <<<1,    b, 0, stream>>>(x, eidx, flags);
    k_init_deg <<<gN,   b, 0, stream>>>(dinv, N);
    k_deg_accum<<<gE,   b, 0, stream>>>(eidx, E, ew, flags, dinv);
    k_dinv     <<<gN,   b, 0, stream>>>(dinv, N);
    k_norm     <<<gE,   b, 0, stream>>>(eidx, E, ew, dinv, flags, nrm);
    k_mm1      <<<gMM,  b, 0, stream>>>(x, W1, flags, dinv, 0, bufA, N);
    k_selfloop <<<gN32, b, 0, stream>>>(bufA, dinv, bufB, N);
    k_scatter  <<<gE32, b, 0, stream>>>(eidx, E, nrm, flags, bufA, bufB);
    k_mmh      <<<gMM,  b, 0, stream>>>(bufB, b1, 1, W2, flags, dinv, 0, bufA, N);
    k_selfloop <<<gN32, b, 0, stream>>>(bufA, dinv, bufB, N);
    k_scatter  <<<gE32, b, 0, stream>>>(eidx, E, nrm, flags, bufA, bufB);
    k_mmh      <<<gMM,  b, 0, stream>>>(bufB, b2, 1, W3, flags, dinv, 0, bufA, N);
    k_selfloop <<<gN32, b, 0, stream>>>(bufA, dinv, bufB, N);
    k_scatter  <<<gE32, b, 0, stream>>>(eidx, E, nrm, flags, bufA, bufB);
    k_pool<<<64, b, 0, stream>>>(bufB, b3, batch, flags, gpool, N);
    k_mlp <<<1,  b, 0, stream>>>(gpool, L1w, L1b, L2w, L2b, L3w, L3b, L4w, L4b, flags, d_out);
  }
}

// Round 8
// 748.519 us; speedup vs baseline: 3.4725x; 3.4725x over previous
//
#include <hip/hip_runtime.h>
#include <hip/hip_bf16.h>

typedef __hip_bfloat16 bf16;

// ---------- dtype-adaptive loads (flags are wave-uniform) ----------
__device__ __forceinline__ float ldf(const void* p, long long i, int f32){
  return f32 ? ((const float*)p)[i] : __bfloat162float(((const bf16*)p)[i]);
}
__device__ __forceinline__ int ldi(const void* p, long long i, int i64){
  return i64 ? (int)((const long long*)p)[i] : ((const int*)p)[i];
}

// ---------- sniff input dtypes once per launch ----------
__global__ void k_sniff(const void* __restrict__ x, const void* __restrict__ eidx,
                        int* __restrict__ flags){
  __shared__ int s_f, s_i;
  if (threadIdx.x == 0){ s_f = 0; s_i = 0; }
  __syncthreads();
  int t = threadIdx.x;
  const unsigned short* u = (const unsigned short*)x;
  int hits = 0;
  for (int k = t; k < 2048; k += 256){
    unsigned short v = u[2*k];
    int e = (v >> 7) & 0xFF;
    if (e == 0xFF || e == 0x00) hits++;
  }
  if (hits) atomicAdd(&s_f, 1);
  const int* ii = (const int*)eidx;
  int nz = 0;
  for (int k = t; k < 1024; k += 256){ if (ii[2*k+1] != 0) nz++; }
  if (nz) atomicAdd(&s_i, 1);
  __syncthreads();
  if (threadIdx.x == 0){
    flags[0] = s_f ? 1 : 0;   // 1 = float32, 0 = bf16
    flags[1] = s_i ? 0 : 1;   // 1 = int64,   0 = int32
  }
}

__global__ void k_zero(int* __restrict__ p, int n){
  int i = blockIdx.x*256 + threadIdx.x;
  if (i < n) p[i] = 0;
}

// ================= binned CSR build =================

__global__ void __launch_bounds__(256) k_bhist(const void* __restrict__ eidx, long long E,
                       const int* __restrict__ flags, int shift, int NB,
                       int* __restrict__ bcnt){
  __shared__ int h[1024];
  int t = threadIdx.x;
  for (int b = t; b < NB; b += 256) h[b] = 0;
  __syncthreads();
  int i64 = flags[1];
  long long e0 = (long long)blockIdx.x*4096;
  long long e1 = e0 + 4096; if (e1 > E) e1 = E;
  for (long long e = e0 + t; e < e1; e += 256){
    int d = ldi(eidx, E + e, i64);
    atomicAdd(&h[d >> shift], 1);
  }
  __syncthreads();
  for (int b = t; b < NB; b += 256) if (h[b]) atomicAdd(&bcnt[b], h[b]);
}

__global__ void __launch_bounds__(256) k_bscan(const int* __restrict__ bcnt, int* __restrict__ bbase,
                       int NB, int E){
  __shared__ int tmp[256];
  int t = threadIdx.x;
  int v0 = (4*t+0 < NB) ? bcnt[4*t+0] : 0;
  int v1 = (4*t+1 < NB) ? bcnt[4*t+1] : 0;
  int v2 = (4*t+2 < NB) ? bcnt[4*t+2] : 0;
  int v3 = (4*t+3 < NB) ? bcnt[4*t+3] : 0;
  int s = v0+v1+v2+v3;
  tmp[t] = s;
  __syncthreads();
  for (int st = 1; st < 256; st <<= 1){
    int add = (t >= st) ? tmp[t-st] : 0;
    __syncthreads();
    tmp[t] += add;
    __syncthreads();
  }
  int run = tmp[t] - s;
  if (4*t+0 < NB){ bbase[4*t+0] = run; run += v0; }
  if (4*t+1 < NB){ bbase[4*t+1] = run; run += v1; }
  if (4*t+2 < NB){ bbase[4*t+2] = run; run += v2; }
  if (4*t+3 < NB){ bbase[4*t+3] = run; run += v3; }
  if (t == 255) bbase[NB] = E;
}

// 2048-edge chunks (34 KB LDS -> 4 blocks/CU): counting-sort by bucket, write runs
#define BINCH 2048
__global__ void __launch_bounds__(256) k_bin(const void* __restrict__ eidx, long long E,
                     const void* __restrict__ ew, const int* __restrict__ flags,
                     int shift, int NB, const int* __restrict__ bbase,
                     int* __restrict__ gcur, int2* __restrict__ csrTmp){
  __shared__ int bst[1024];
  __shared__ int bcur[1024];
  __shared__ int gof[1024];
  __shared__ int tmp[256];
  __shared__ int2 ent[BINCH];
  __shared__ unsigned short entb[BINCH];
  int t = threadIdx.x;
  int i64 = flags[1], f32 = flags[0];
  long long e0 = (long long)blockIdx.x*BINCH;
  int cnt = (int)(((E - e0) < BINCH) ? (E - e0) : BINCH);
  int msk = (1 << shift) - 1;
  for (int b = t; b < NB; b += 256) bst[b] = 0;
  __syncthreads();
  for (int i = t; i < cnt; i += 256){
    int d = ldi(eidx, E + e0 + i, i64);
    atomicAdd(&bst[d >> shift], 1);
  }
  __syncthreads();
  int v0 = (4*t+0 < NB) ? bst[4*t+0] : 0;
  int v1 = (4*t+1 < NB) ? bst[4*t+1] : 0;
  int v2 = (4*t+2 < NB) ? bst[4*t+2] : 0;
  int v3 = (4*t+3 < NB) ? bst[4*t+3] : 0;
  int s = v0+v1+v2+v3;
  tmp[t] = s;
  __syncthreads();
  for (int st = 1; st < 256; st <<= 1){
    int add = (t >= st) ? tmp[t-st] : 0;
    __syncthreads();
    tmp[t] += add;
    __syncthreads();
  }
  int run = tmp[t] - s;
  __syncthreads();
  if (4*t+0 < NB){ bst[4*t+0]=run; bcur[4*t+0]=run; if (v0) gof[4*t+0]=atomicAdd(&gcur[4*t+0], v0); run += v0; }
  if (4*t+1 < NB){ bst[4*t+1]=run; bcur[4*t+1]=run; if (v1) gof[4*t+1]=atomicAdd(&gcur[4*t+1], v1); run += v1; }
  if (4*t+2 < NB){ bst[4*t+2]=run; bcur[4*t+2]=run; if (v2) gof[4*t+2]=atomicAdd(&gcur[4*t+2], v2); run += v2; }
  if (4*t+3 < NB){ bst[4*t+3]=run; bcur[4*t+3]=run; if (v3) gof[4*t+3]=atomicAdd(&gcur[4*t+3], v3); run += v3; }
  __syncthreads();
  for (int i = t; i < cnt; i += 256){
    int d  = ldi(eidx, E + e0 + i, i64);
    int sc = ldi(eidx, e0 + i, i64);
    float w = ldf(ew, e0 + i, f32);
    int b = d >> shift;
    int dl = d & msk;
    int pos = atomicAdd(&bcur[b], 1);
    ent[pos]  = make_int2((dl << 24) | sc, __float_as_int(w));
    entb[pos] = (unsigned short)b;
  }
  __syncthreads();
  for (int i = t; i < cnt; i += 256){
    int b = entb[i];
    int gpos = bbase[b] + gof[b] + (i - bst[b]);
    csrTmp[gpos] = ent[i];
  }
}

// per-bucket: counting sort by dst-low; deg/dinv/rowptr in-pass; csr.y = w*dinv[dst]
__global__ void __launch_bounds__(256) k_bucket(const int2* __restrict__ csrTmp, const int* __restrict__ bbase,
                        int shift, int N, int E, int2* __restrict__ csr,
                        int* __restrict__ rowptr, float* __restrict__ dinv){
  __shared__ int   h[256];
  __shared__ int   st[256];
  __shared__ int   cur[256];
  __shared__ float wsum[256];
  __shared__ float sdv[256];
  int b = blockIdx.x, t = threadIdx.x;
  int base = bbase[b], cnt = bbase[b+1] - base;
  h[t] = 0; wsum[t] = 0.f;
  __syncthreads();
  for (int i = t; i < cnt; i += 256){
    int2 p = csrTmp[base + i];
    int dl = ((unsigned)p.x) >> 24;
    atomicAdd(&h[dl], 1);
    atomicAdd(&wsum[dl], __int_as_float(p.y));
  }
  __syncthreads();
  int c = h[t];
  st[t] = c;
  __syncthreads();
  for (int s2 = 1; s2 < 256; s2 <<= 1){
    int add = (t >= s2) ? st[t-s2] : 0;
    __syncthreads();
    st[t] += add;
    __syncthreads();
  }
  int ex = st[t] - c;
  cur[t] = ex;
  int n = (b << shift) + t;
  if (t < (1 << shift) && n < N){
    float deg = 1.f + wsum[t];
    float di = (deg > 0.f) ? rsqrtf(fmaxf(deg, 1e-30f)) : 0.f;
    sdv[t] = di;
    dinv[n] = di;
    rowptr[n] = base + ex;
    if (n == N-1) rowptr[N] = E;
  }
  __syncthreads();
  for (int i = t; i < cnt; i += 256){
    int2 p = csrTmp[base + i];
    int dl = ((unsigned)p.x) >> 24;
    int pos = atomicAdd(&cur[dl], 1);
    float nm = __int_as_float(p.y) * sdv[dl];       // w * dinv[dst]
    csr[base + pos] = make_int2(p.x & 0xFFFFFF, __float_as_int(nm));
  }
}

// ---------- pull: wave/node. zp = dinv*(hW); agg[n] = dinv[n]*zp[n] + sum csr.y*zp[src] ----------
__global__ void k_pull(const int2* __restrict__ csr, const int* __restrict__ rowptr,
                       const float* __restrict__ dinv, const float* __restrict__ zp,
                       float* __restrict__ agg, int N){
  int n = blockIdx.x*4 + (threadIdx.x >> 6);
  int lane = threadIdx.x & 63;
  if (n >= N) return;
  int g = lane >> 3;            // edge subgroup 0..7
  int q = lane & 7;             // feature quad 0..7
  const float4* h4 = (const float4*)zp;
  int s0 = rowptr[n], s1 = rowptr[n+1];
  float4 acc = make_float4(0.f,0.f,0.f,0.f);
  if (g == 0){
    float di = dinv[n];
    float4 hv = h4[(long long)n*8 + q];
    acc.x = di*hv.x; acc.y = di*hv.y; acc.z = di*hv.z; acc.w = di*hv.w;
  }
  for (int j = s0 + g; j < s1; j += 8){
    int2 p = csr[j];
    float nm = __int_as_float(p.y);
    float4 hv = h4[(long long)p.x*8 + q];
    acc.x = fmaf(nm, hv.x, acc.x);
    acc.y = fmaf(nm, hv.y, acc.y);
    acc.z = fmaf(nm, hv.z, acc.z);
    acc.w = fmaf(nm, hv.w, acc.w);
  }
  #pragma unroll
  for (int st = 8; st < 64; st <<= 1){
    acc.x += __shfl_xor(acc.x, st, 64);
    acc.y += __shfl_xor(acc.y, st, 64);
    acc.z += __shfl_xor(acc.z, st, 64);
    acc.w += __shfl_xor(acc.w, st, 64);
  }
  if (g == 0) ((float4*)agg)[(long long)n*8 + q] = acc;
}

// ---------- layer-1 matmul: 32 rows/block, 4 outputs/thread; K=128, F=32 ----------
__global__ void k_mm1(const void* __restrict__ x, const void* __restrict__ W,
                      const int* __restrict__ flags, const float* __restrict__ dinv,
                      int mul_dinv, float* __restrict__ out, int N){
  __shared__ float Ws[128*32];
  __shared__ float xs[32*128];
  int tid = threadIdx.x;
  int f32 = flags[0];
  for (int i = tid; i < 4096; i += 256) Ws[i] = ldf(W, i, f32);
  int n0 = blockIdx.x*32;
  for (int i = tid; i < 4096; i += 256){
    int r = i >> 7, k = i & 127, n = n0 + r;
    xs[i] = (n < N) ? ldf(x, (long long)n*128 + k, f32) : 0.f;
  }
  __syncthreads();
  int f = tid & 31, r = tid >> 5;
  float a0=0.f, a1=0.f, a2=0.f, a3=0.f;
  for (int k = 0; k < 128; ++k){
    float w = Ws[k*32+f];
    a0 = fmaf(xs[(r    )*128+k], w, a0);
    a1 = fmaf(xs[(r+ 8)*128+k], w, a1);
    a2 = fmaf(xs[(r+16)*128+k], w, a2);
    a3 = fmaf(xs[(r+24)*128+k], w, a3);
  }
  int n;
  n = n0+r;    if (n < N) out[n*32+f] = mul_dinv ? a0*dinv[n] : a0;
  n = n0+r+8;  if (n < N) out[n*32+f] = mul_dinv ? a1*dinv[n] : a1;
  n = n0+r+16; if (n < N) out[n*32+f] = mul_dinv ? a2*dinv[n] : a2;
  n = n0+r+24; if (n < N) out[n*32+f] = mul_dinv ? a3*dinv[n] : a3;
}

// ---------- hidden matmul: 32 rows/block; prev layer's bias+relu fused into input ----------
__global__ void k_mmh(const float* __restrict__ in, const void* __restrict__ bias, int do_relu,
                      const void* __restrict__ W, const int* __restrict__ flags,
                      const float* __restrict__ dinv, int mul_dinv,
                      float* __restrict__ out, int N){
  __shared__ float Ws[32*32];
  __shared__ float xs[32*32];
  int tid = threadIdx.x;
  int f32 = flags[0];
  for (int i = tid; i < 1024; i += 256) Ws[i] = ldf(W, i, f32);
  int n0 = blockIdx.x*32;
  for (int i = tid; i < 1024; i += 256){
    int r = i >> 5, k = i & 31, n = n0 + r;
    float v = 0.f;
    if (n < N){
      v = in[n*32+k] + ldf(bias, k, f32);
      if (do_relu) v = fmaxf(v, 0.f);
    }
    xs[i] = v;
  }
  __syncthreads();
  int f = tid & 31, r = tid >> 5;
  float a0=0.f, a1=0.f, a2=0.f, a3=0.f;
  for (int k = 0; k < 32; ++k){
    float w = Ws[k*32+f];
    a0 = fmaf(xs[(r    )*32+k], w, a0);
    a1 = fmaf(xs[(r+ 8)*32+k], w, a1);
    a2 = fmaf(xs[(r+16)*32+k], w, a2);
    a3 = fmaf(xs[(r+24)*32+k], w, a3);
  }
  int n;
  n = n0+r;    if (n < N) out[n*32+f] = mul_dinv ? a0*dinv[n] : a0;
  n = n0+r+8;  if (n < N) out[n*32+f] = mul_dinv ? a1*dinv[n] : a1;
  n = n0+r+16; if (n < N) out[n*32+f] = mul_dinv ? a2*dinv[n] : a2;
  n = n0+r+24; if (n < N) out[n*32+f] = mul_dinv ? a3*dinv[n] : a3;
}

// ---------- mean pool per graph (batch sorted) ----------
__device__ __forceinline__ int lower_bound_i(const void* __restrict__ a, int n, int v, int i64){
  int lo = 0, hi = n;
  while (lo < hi){ int mid = (lo+hi) >> 1; if (ldi(a, mid, i64) < v) lo = mid+1; else hi = mid; }
  return lo;
}

__global__ void k_pool(const float* __restrict__ agg, const void* __restrict__ b3,
                       const void* __restrict__ batch, const int* __restrict__ flags,
                       float* __restrict__ gpool, int N){
  int f32 = flags[0], i64 = flags[1];
  int g = blockIdx.x;
  int start = lower_bound_i(batch, N, g, i64);
  int end   = lower_bound_i(batch, N, g+1, i64);
  int tid = threadIdx.x;
  int f = tid & 31, r = tid >> 5;
  float acc = 0.f;
  for (int n = start + r; n < end; n += 8) acc += agg[n*32+f];
  __shared__ float red[8][32];
  red[r][f] = acc;
  __syncthreads();
  if (r == 0){
    float s = red[0][f];
    #pragma unroll
    for (int j = 1; j < 8; ++j) s += red[j][f];
    int c = end - start;
    float gv = (c > 0) ? (s / (float)c + ldf(b3, f, f32)) : 0.f;
    gpool[g*32+f] = gv;
  }
}

// ---------- MLP head: 1 block, column-per-thread, 16 row-accumulators (ILP) ----------
__global__ void __launch_bounds__(256, 1) k_mlp(const float* __restrict__ gpool,
                      const void* __restrict__ L1w, const void* __restrict__ L1b,
                      const void* __restrict__ L2w, const void* __restrict__ L2b,
                      const void* __restrict__ L3w, const void* __restrict__ L3b,
                      const void* __restrict__ L4w, const void* __restrict__ L4b,
                      const int* __restrict__ flags, void* __restrict__ out){
  __shared__ float gin[64*32];
  __shared__ float A[64*65];
  __shared__ float B[64*65];
  __shared__ float ws[64*64];
  __shared__ float wb[64];
  int tid = threadIdx.x;
  int f32 = flags[0];
  int j  = tid & 63;
  int i0 = tid >> 6;
  float acc[16];

  for (int i = tid; i < 64*32; i += 256) gin[i] = gpool[i];
  for (int i = tid; i < 2048; i += 256) ws[i] = ldf(L1w, i, f32);
  if (tid < 64) wb[tid] = ldf(L1b, tid, f32);
  __syncthreads();
  #pragma unroll
  for (int r = 0; r < 16; ++r) acc[r] = wb[j];
  for (int k = 0; k < 32; ++k){
    float w = ws[k*64+j];
    #pragma unroll
    for (int r = 0; r < 16; ++r) acc[r] = fmaf(gin[(i0+4*r)*32+k], w, acc[r]);
  }
  #pragma unroll
  for (int r = 0; r < 16; ++r) A[(i0+4*r)*65+j] = fmaxf(acc[r], 0.f);
  __syncthreads();
  for (int i = tid; i < 4096; i += 256) ws[i] = ldf(L2w, i, f32);
  if (tid < 64) wb[tid] = ldf(L2b, tid, f32);
  __syncthreads();
  #pragma unroll
  for (int r = 0; r < 16; ++r) acc[r] = wb[j];
  for (int k = 0; k < 64; ++k){
    float w = ws[k*64+j];
    #pragma unroll
    for (int r = 0; r < 16; ++r) acc[r] = fmaf(A[(i0+4*r)*65+k], w, acc[r]);
  }
  #pragma unroll
  for (int r = 0; r < 16; ++r) B[(i0+4*r)*65+j] = fmaxf(acc[r], 0.f);
  __syncthreads();
  for (int i = tid; i < 4096; i += 256) ws[i] = ldf(L3w, i, f32);
  if (tid < 64) wb[tid] = ldf(L3b, tid, f32);
  __syncthreads();
  #pragma unroll
  for (int r = 0; r < 16; ++r) acc[r] = wb[j];
  for (int k = 0; k < 64; ++k){
    float w = ws[k*64+j];
    #pragma unroll
    for (int r = 0; r < 16; ++r) acc[r] = fmaf(B[(i0+4*r)*65+k], w, acc[r]);
  }
  #pragma unroll
  for (int r = 0; r < 16; ++r) A[(i0+4*r)*65+j] = fmaxf(acc[r], 0.f);
  __syncthreads();
  for (int i = tid; i < 640; i += 256) ws[i] = ldf(L4w, i, f32);
  if (tid < 10) wb[tid] = ldf(L4b, tid, f32);
  __syncthreads();
  if (tid < 64){
    int row = tid;
    float a10[10];
    #pragma unroll
    for (int c = 0; c < 10; ++c) a10[c] = wb[c];
    for (int k = 0; k < 64; ++k){
      float av = A[row*65+k];
      #pragma unroll
      for (int c = 0; c < 10; ++c) a10[c] = fmaf(av, ws[k*10+c], a10[c]);
    }
    #pragma unroll
    for (int c = 0; c < 10; ++c){
      if (f32) ((float*)out)[row*10+c] = a10[c];
      else     ((bf16*)out)[row*10+c]  = __float2bfloat16(a10[c]);
    }
  }
}

// ---------- fallback (atomic-scatter path, small ws) ----------
__global__ void k_init_deg(float* __restrict__ deg, int N){
  int i = blockIdx.x*256 + threadIdx.x;
  if (i < N) deg[i] = 1.0f;
}
__global__ void k_deg_accum(const void* __restrict__ eidx, long long E,
                            const void* __restrict__ w, const int* __restrict__ flags,
                            float* __restrict__ deg){
  long long e = (long long)blockIdx.x*256 + threadIdx.x;
  if (e < E){
    int f32 = flags[0], i64 = flags[1];
    atomicAdd(&deg[ldi(eidx, E + e, i64)], ldf(w, e, f32));
  }
}
__global__ void k_dinv(float* __restrict__ deg, int N){
  int i = blockIdx.x*256 + threadIdx.x;
  if (i < N){
    float d = deg[i];
    deg[i] = (d > 0.f) ? rsqrtf(fmaxf(d, 1e-30f)) : 0.f;
  }
}
__global__ void k_norm(const void* __restrict__ eidx, long long E,
                       const void* __restrict__ w, const float* __restrict__ dinv,
                       const int* __restrict__ flags, float* __restrict__ nrm){
  long long e = (long long)blockIdx.x*256 + threadIdx.x;
  if (e < E){
    int f32 = flags[0], i64 = flags[1];
    int s = ldi(eidx, e, i64), d = ldi(eidx, E + e, i64);
    nrm[e] = dinv[s] * ldf(w, e, f32) * dinv[d];
  }
}
__global__ void k_selfloop(const float* __restrict__ hlin, const float* __restrict__ dinv,
                           float* __restrict__ agg, int N){
  int idx = blockIdx.x*256 + threadIdx.x;
  if (idx < N*32){
    int n = idx >> 5;
    float di = dinv[n];
    agg[idx] = di*di*hlin[idx];
  }
}
__global__ void k_scatter(const void* __restrict__ eidx, long long E,
                          const float* __restrict__ nrm, const int* __restrict__ flags,
                          const float* __restrict__ hlin, float* __restrict__ agg){
  long long idx = (long long)blockIdx.x*256 + threadIdx.x;
  if (idx < E*32){
    int i64 = flags[1];
    long long e = idx >> 5;
    int f = (int)(idx & 31);
    int s = ldi(eidx, e, i64), d = ldi(eidx, E + e, i64);
    atomicAdd(&agg[(long long)d*32 + f], nrm[e] * hlin[(long long)s*32 + f]);
  }
}

extern "C" void kernel_launch(void* const* d_in, const int* in_sizes, int n_in,
                              void* d_out, int out_size, void* d_ws, size_t ws_size,
                              hipStream_t stream){
  const void* x   = d_in[0];
  const void* ew  = d_in[1];
  const void* W1  = d_in[2];
  const void* b1  = d_in[3];
  const void* W2  = d_in[4];
  const void* b2  = d_in[5];
  const void* W3  = d_in[6];
  const void* b3  = d_in[7];
  const void* L1w = d_in[8];  const void* L1b = d_in[9];
  const void* L2w = d_in[10]; const void* L2b = d_in[11];
  const void* L3w = d_in[12]; const void* L3b = d_in[13];
  const void* L4w = d_in[14]; const void* L4b = d_in[15];
  const void* eidx  = d_in[16];
  const void* batch = d_in[17];
  const long long E = in_sizes[1];
  const int N = in_sizes[17];

  dim3 b(256);
  int gN   = (N + 255)/256;
  int gE   = (int)((E + 255)/256);
  int gMM  = (N + 31)/32;
  int gNd4 = (N + 3)/4;
  int gBH  = (int)((E + 4095)/4096);
  int gBN  = (int)((E + BINCH - 1)/BINCH);

  const int shift = 7;                       // 128-node buckets
  int NB = (N + 127) >> 7;

  auto AL = [](size_t v){ return (v + 255) & ~(size_t)255; };

  char* base = (char*)d_ws;
  size_t off = 0;
  size_t o_flags = off; off += AL(64*4);
  size_t o_rowp  = off; off += AL((size_t)(N+1)*4);
  size_t o_dinv  = off; off += AL((size_t)N*4);
  size_t o_bbase = off; off += AL((size_t)(NB+1)*4);
  size_t o_bcnt  = off; off += AL((size_t)NB*4) + AL((size_t)NB*4);   // bcnt + gcur
  size_t o_csr   = off; off += AL((size_t)E*8);
  size_t o_tmp   = off; off += AL((size_t)E*8);
  size_t o_bufA  = off; off += AL((size_t)N*128);
  size_t o_bufB  = off; off += AL((size_t)N*128);
  size_t o_gp    = off; off += AL(2048*4);
  size_t needed  = off;

  if (ws_size >= needed && NB <= 1024 && N < (1<<24)){
    int*   flags  = (int*)(base + o_flags);
    int*   rowptr = (int*)(base + o_rowp);
    float* dinv   = (float*)(base + o_dinv);
    int*   bbase  = (int*)(base + o_bbase);
    int*   bcnt   = (int*)(base + o_bcnt);
    int*   gcur   = (int*)(base + o_bcnt + AL((size_t)NB*4));
    int2*  csr    = (int2*)(base + o_csr);
    int2*  csrTmp = (int2*)(base + o_tmp);
    float* bufA   = (float*)(base + o_bufA);
    float* bufB   = (float*)(base + o_bufB);
    float* gpool  = (float*)(base + o_gp);

    k_sniff <<<1,    b, 0, stream>>>(x, eidx, flags);
    k_zero  <<<(int)((AL((size_t)NB*4)/4 + NB + 255)/256), b, 0, stream>>>(bcnt, (int)(AL((size_t)NB*4)/4 + NB));
    k_bhist <<<gBH,  b, 0, stream>>>(eidx, E, flags, shift, NB, bcnt);
    k_bscan <<<1,    b, 0, stream>>>(bcnt, bbase, NB, (int)E);
    k_bin   <<<gBN,  b, 0, stream>>>(eidx, E, ew, flags, shift, NB, bbase, gcur, csrTmp);
    k_bucket<<<NB,   b, 0, stream>>>(csrTmp, bbase, shift, N, (int)E, csr, rowptr, dinv);
    // layer 1
    k_mm1   <<<gMM,  b, 0, stream>>>(x, W1, flags, dinv, 1, bufA, N);
    k_pull  <<<gNd4, b, 0, stream>>>(csr, rowptr, dinv, bufA, bufB, N);
    // layer 2
    k_mmh   <<<gMM,  b, 0, stream>>>(bufB, b1, 1, W2, flags, dinv, 1, bufA, N);
    k_pull  <<<gNd4, b, 0, stream>>>(csr, rowptr, dinv, bufA, bufB, N);
    // layer 3
    k_mmh   <<<gMM,  b, 0, stream>>>(bufB, b2, 1, W3, flags, dinv, 1, bufA, N);
    k_pull  <<<gNd4, b, 0, stream>>>(csr, rowptr, dinv, bufA, bufB, N);
    // head
    k_pool<<<64, b, 0, stream>>>(bufB, b3, batch, flags, gpool, N);
    k_mlp <<<1,  b, 0, stream>>>(gpool, L1w, L1b, L2w, L2b, L3w, L3b, L4w, L4b, flags, d_out);
    return;
  }

  // ---- fallback: atomic-scatter path ----
  {
    float* wf    = (float*)d_ws;
    int*   flags = (int*)d_ws;
    size_t Npad  = ((size_t)N + 255) & ~(size_t)255;
    float* dinv  = wf + 64;
    float* nrm   = dinv + Npad;
    float* bufA  = nrm + E;
    float* bufB  = bufA + (size_t)N*32;
    float* gpool = bufB + (size_t)N*32;
    int gN32 = (N*32 + 255)/256;
    int gE32 = (int)((E*32 + 255)/256);

    k_sniff    <<<1,    b, 0, stream>>>(x, eidx, flags);
    k_init_deg <<<gN,   b, 0, stream>>>(dinv, N);
    k_deg_accum<<<gE,   b, 0, stream>>>(eidx, E, ew, flags, dinv);
    k_dinv     <<<gN,   b, 0, stream>>>(dinv, N);
    k_norm     <<<gE,   b, 0, stream>>>(eidx, E, ew, dinv, flags, nrm);
    k_mm1      <<<gMM,  b, 0, stream>>>(x, W1, flags, dinv, 0, bufA, N);
    k_selfloop <<<gN32, b, 0, stream>>>(bufA, dinv, bufB, N);
    k_scatter  <<<gE32, b, 0, stream>>>(eidx, E, nrm, flags, bufA, bufB);
    k_mmh      <<<gMM,  b, 0, stream>>>(bufB, b1, 1, W2, flags, dinv, 0, bufA, N);
    k_selfloop <<<gN32, b, 0, stream>>>(bufA, dinv, bufB, N);
    k_scatter  <<<gE32, b, 0, stream>>>(eidx, E, nrm, flags, bufA, bufB);
    k_mmh      <<<gMM,  b, 0, stream>>>(bufB, b2, 1, W3, flags, dinv, 0, bufA, N);
    k_selfloop <<<gN32, b, 0, stream>>>(bufA, dinv, bufB, N);
    k_scatter  <<<gE32, b, 0, stream>>>(eidx, E, nrm, flags, bufA, bufB);
    k_pool<<<64, b, 0, stream>>>(bufB, b3, batch, flags, gpool, N);
    k_mlp <<<1,  b, 0, stream>>>(gpool, L1w, L1b, L2w, L2b, L3w, L3b, L4w, L4b, flags, d_out);
  }
}

// Round 9
// 685.691 us; speedup vs baseline: 3.7906x; 1.0916x over previous
//
#include <hip/hip_runtime.h>
#include <hip/hip_bf16.h>

typedef __hip_bfloat16 bf16;

// ---------- dtype-adaptive loads (flags are wave-uniform) ----------
__device__ __forceinline__ float ldf(const void* p, long long i, int f32){
  return f32 ? ((const float*)p)[i] : __bfloat162float(((const bf16*)p)[i]);
}
__device__ __forceinline__ int ldi(const void* p, long long i, int i64){
  return i64 ? (int)((const long long*)p)[i] : ((const int*)p)[i];
}

// ---------- sniff input dtypes once per launch ----------
__global__ void k_sniff(const void* __restrict__ x, const void* __restrict__ eidx,
                        int* __restrict__ flags){
  __shared__ int s_f, s_i;
  if (threadIdx.x == 0){ s_f = 0; s_i = 0; }
  __syncthreads();
  int t = threadIdx.x;
  const unsigned short* u = (const unsigned short*)x;
  int hits = 0;
  for (int k = t; k < 2048; k += 256){
    unsigned short v = u[2*k];
    int e = (v >> 7) & 0xFF;
    if (e == 0xFF || e == 0x00) hits++;
  }
  if (hits) atomicAdd(&s_f, 1);
  const int* ii = (const int*)eidx;
  int nz = 0;
  for (int k = t; k < 1024; k += 256){ if (ii[2*k+1] != 0) nz++; }
  if (nz) atomicAdd(&s_i, 1);
  __syncthreads();
  if (threadIdx.x == 0){
    flags[0] = s_f ? 1 : 0;   // 1 = float32, 0 = bf16
    flags[1] = s_i ? 0 : 1;   // 1 = int64,   0 = int32
  }
}

__global__ void k_zero(int* __restrict__ p, int n){
  int i = blockIdx.x*256 + threadIdx.x;
  if (i < n) p[i] = 0;
}

// ================= binned CSR build (shift=8: 256-node buckets) =================

__global__ void __launch_bounds__(256) k_bhist(const void* __restrict__ eidx, long long E,
                       const int* __restrict__ flags, int shift, int NB,
                       int* __restrict__ bcnt){
  __shared__ int h[1024];
  int t = threadIdx.x;
  for (int b = t; b < NB; b += 256) h[b] = 0;
  __syncthreads();
  int i64 = flags[1];
  long long e0 = (long long)blockIdx.x*4096;
  long long e1 = e0 + 4096; if (e1 > E) e1 = E;
  for (long long e = e0 + t; e < e1; e += 256){
    int d = ldi(eidx, E + e, i64);
    atomicAdd(&h[d >> shift], 1);
  }
  __syncthreads();
  for (int b = t; b < NB; b += 256) if (h[b]) atomicAdd(&bcnt[b], h[b]);
}

__global__ void __launch_bounds__(256) k_bscan(const int* __restrict__ bcnt, int* __restrict__ bbase,
                       int NB, int E){
  __shared__ int tmp[256];
  int t = threadIdx.x;
  int v0 = (4*t+0 < NB) ? bcnt[4*t+0] : 0;
  int v1 = (4*t+1 < NB) ? bcnt[4*t+1] : 0;
  int v2 = (4*t+2 < NB) ? bcnt[4*t+2] : 0;
  int v3 = (4*t+3 < NB) ? bcnt[4*t+3] : 0;
  int s = v0+v1+v2+v3;
  tmp[t] = s;
  __syncthreads();
  for (int st = 1; st < 256; st <<= 1){
    int add = (t >= st) ? tmp[t-st] : 0;
    __syncthreads();
    tmp[t] += add;
    __syncthreads();
  }
  int run = tmp[t] - s;
  if (4*t+0 < NB){ bbase[4*t+0] = run; run += v0; }
  if (4*t+1 < NB){ bbase[4*t+1] = run; run += v1; }
  if (4*t+2 < NB){ bbase[4*t+2] = run; run += v2; }
  if (4*t+3 < NB){ bbase[4*t+3] = run; run += v3; }
  if (t == 255) bbase[NB] = E;
}

// 4096-edge chunks: LDS counting-sort by bucket, write run-contiguous into csrTmp
#define BINCH 4096
__global__ void __launch_bounds__(256) k_bin(const void* __restrict__ eidx, long long E,
                     const void* __restrict__ ew, const int* __restrict__ flags,
                     int shift, int NB, const int* __restrict__ bbase,
                     int* __restrict__ gcur, int2* __restrict__ csrTmp){
  __shared__ int bst[512];
  __shared__ int bcur[512];
  __shared__ int gof[512];
  __shared__ int tmp[256];
  __shared__ int2 ent[BINCH];
  __shared__ unsigned short entb[BINCH];
  int t = threadIdx.x;
  int i64 = flags[1], f32 = flags[0];
  long long e0 = (long long)blockIdx.x*BINCH;
  int cnt = (int)(((E - e0) < BINCH) ? (E - e0) : BINCH);
  int msk = (1 << shift) - 1;
  for (int b = t; b < NB; b += 256) bst[b] = 0;
  __syncthreads();
  for (int i = t; i < cnt; i += 256){
    int d = ldi(eidx, E + e0 + i, i64);
    atomicAdd(&bst[d >> shift], 1);
  }
  __syncthreads();
  int v0 = (2*t+0 < NB) ? bst[2*t+0] : 0;
  int v1 = (2*t+1 < NB) ? bst[2*t+1] : 0;
  int s = v0+v1;
  tmp[t] = s;
  __syncthreads();
  for (int st = 1; st < 256; st <<= 1){
    int add = (t >= st) ? tmp[t-st] : 0;
    __syncthreads();
    tmp[t] += add;
    __syncthreads();
  }
  int run = tmp[t] - s;
  __syncthreads();
  if (2*t+0 < NB){ bst[2*t+0]=run; bcur[2*t+0]=run; if (v0) gof[2*t+0]=atomicAdd(&gcur[2*t+0], v0); run += v0; }
  if (2*t+1 < NB){ bst[2*t+1]=run; bcur[2*t+1]=run; if (v1) gof[2*t+1]=atomicAdd(&gcur[2*t+1], v1); run += v1; }
  __syncthreads();
  for (int i = t; i < cnt; i += 256){
    int d  = ldi(eidx, E + e0 + i, i64);
    int sc = ldi(eidx, e0 + i, i64);
    float w = ldf(ew, e0 + i, f32);
    int b = d >> shift;
    int dl = d & msk;
    int pos = atomicAdd(&bcur[b], 1);
    ent[pos]  = make_int2((dl << 24) | sc, __float_as_int(w));
    entb[pos] = (unsigned short)b;
  }
  __syncthreads();
  for (int i = t; i < cnt; i += 256){
    int b = entb[i];
    int gpos = bbase[b] + gof[b] + (i - bst[b]);
    csrTmp[gpos] = ent[i];
  }
}

// per-bucket: counting sort by dst-low (0..255); deg/dinv/rowptr in-pass; csr.y = w*dinv[dst]
__global__ void __launch_bounds__(256) k_bucket(const int2* __restrict__ csrTmp, const int* __restrict__ bbase,
                        int shift, int N, int E, int2* __restrict__ csr,
                        int* __restrict__ rowptr, float* __restrict__ dinv){
  __shared__ int   h[256];
  __shared__ int   st[256];
  __shared__ int   cur[256];
  __shared__ float wsum[256];
  __shared__ float sdv[256];
  int b = blockIdx.x, t = threadIdx.x;
  int base = bbase[b], cnt = bbase[b+1] - base;
  h[t] = 0; wsum[t] = 0.f;
  __syncthreads();
  for (int i = t; i < cnt; i += 256){
    int2 p = csrTmp[base + i];
    int dl = ((unsigned)p.x) >> 24;
    atomicAdd(&h[dl], 1);
    atomicAdd(&wsum[dl], __int_as_float(p.y));
  }
  __syncthreads();
  int c = h[t];
  st[t] = c;
  __syncthreads();
  for (int s2 = 1; s2 < 256; s2 <<= 1){
    int add = (t >= s2) ? st[t-s2] : 0;
    __syncthreads();
    st[t] += add;
    __syncthreads();
  }
  int ex = st[t] - c;
  cur[t] = ex;
  int n = (b << shift) + t;
  if (n < N){
    float deg = 1.f + wsum[t];
    float di = (deg > 0.f) ? rsqrtf(fmaxf(deg, 1e-30f)) : 0.f;
    sdv[t] = di;
    dinv[n] = di;
    rowptr[n] = base + ex;
    if (n == N-1) rowptr[N] = E;
  }
  __syncthreads();
  for (int i = t; i < cnt; i += 256){
    int2 p = csrTmp[base + i];
    int dl = ((unsigned)p.x) >> 24;
    int pos = atomicAdd(&cur[dl], 1);
    float nm = __int_as_float(p.y) * sdv[dl];       // w * dinv[dst]
    csr[base + pos] = make_int2(p.x & 0xFFFFFF, __float_as_int(nm));
  }
}

// ---------- pull: wave/node, 2-way unrolled to overlap csr-load + row-gather latency ----------
// zp = dinv*(hW); agg[n] = dinv[n]*zp[n] + sum csr.y*zp[src]
__global__ void k_pull(const int2* __restrict__ csr, const int* __restrict__ rowptr,
                       const float* __restrict__ dinv, const float* __restrict__ zp,
                       float* __restrict__ agg, int N){
  int n = blockIdx.x*4 + (threadIdx.x >> 6);
  int lane = threadIdx.x & 63;
  if (n >= N) return;
  int g = lane >> 3;            // edge subgroup 0..7
  int q = lane & 7;             // feature quad 0..7
  const float4* h4 = (const float4*)zp;
  int s0 = rowptr[n], s1 = rowptr[n+1];
  float4 acc = make_float4(0.f,0.f,0.f,0.f);
  if (g == 0){
    float di = dinv[n];
    float4 hv = h4[(long long)n*8 + q];
    acc.x = di*hv.x; acc.y = di*hv.y; acc.z = di*hv.z; acc.w = di*hv.w;
  }
  int j = s0 + g;
  for (; j + 8 < s1; j += 16){
    int2 p0 = csr[j];
    int2 p1 = csr[j+8];
    float nm0 = __int_as_float(p0.y);
    float nm1 = __int_as_float(p1.y);
    float4 h0 = h4[(long long)p0.x*8 + q];
    float4 h1 = h4[(long long)p1.x*8 + q];
    acc.x = fmaf(nm0, h0.x, acc.x); acc.y = fmaf(nm0, h0.y, acc.y);
    acc.z = fmaf(nm0, h0.z, acc.z); acc.w = fmaf(nm0, h0.w, acc.w);
    acc.x = fmaf(nm1, h1.x, acc.x); acc.y = fmaf(nm1, h1.y, acc.y);
    acc.z = fmaf(nm1, h1.z, acc.z); acc.w = fmaf(nm1, h1.w, acc.w);
  }
  if (j < s1){
    int2 p = csr[j];
    float nm = __int_as_float(p.y);
    float4 hv = h4[(long long)p.x*8 + q];
    acc.x = fmaf(nm, hv.x, acc.x); acc.y = fmaf(nm, hv.y, acc.y);
    acc.z = fmaf(nm, hv.z, acc.z); acc.w = fmaf(nm, hv.w, acc.w);
  }
  #pragma unroll
  for (int st = 8; st < 64; st <<= 1){
    acc.x += __shfl_xor(acc.x, st, 64);
    acc.y += __shfl_xor(acc.y, st, 64);
    acc.z += __shfl_xor(acc.z, st, 64);
    acc.w += __shfl_xor(acc.w, st, 64);
  }
  if (g == 0) ((float4*)agg)[(long long)n*8 + q] = acc;
}

// ---------- layer-1 matmul: 32 rows/block, 4 outputs/thread; K=128, F=32 ----------
__global__ void k_mm1(const void* __restrict__ x, const void* __restrict__ W,
                      const int* __restrict__ flags, const float* __restrict__ dinv,
                      int mul_dinv, float* __restrict__ out, int N){
  __shared__ float Ws[128*32];
  __shared__ float xs[32*128];
  int tid = threadIdx.x;
  int f32 = flags[0];
  for (int i = tid; i < 4096; i += 256) Ws[i] = ldf(W, i, f32);
  int n0 = blockIdx.x*32;
  for (int i = tid; i < 4096; i += 256){
    int r = i >> 7, k = i & 127, n = n0 + r;
    xs[i] = (n < N) ? ldf(x, (long long)n*128 + k, f32) : 0.f;
  }
  __syncthreads();
  int f = tid & 31, r = tid >> 5;
  float a0=0.f, a1=0.f, a2=0.f, a3=0.f;
  for (int k = 0; k < 128; ++k){
    float w = Ws[k*32+f];
    a0 = fmaf(xs[(r    )*128+k], w, a0);
    a1 = fmaf(xs[(r+ 8)*128+k], w, a1);
    a2 = fmaf(xs[(r+16)*128+k], w, a2);
    a3 = fmaf(xs[(r+24)*128+k], w, a3);
  }
  int n;
  n = n0+r;    if (n < N) out[n*32+f] = mul_dinv ? a0*dinv[n] : a0;
  n = n0+r+8;  if (n < N) out[n*32+f] = mul_dinv ? a1*dinv[n] : a1;
  n = n0+r+16; if (n < N) out[n*32+f] = mul_dinv ? a2*dinv[n] : a2;
  n = n0+r+24; if (n < N) out[n*32+f] = mul_dinv ? a3*dinv[n] : a3;
}

// ---------- hidden matmul: 32 rows/block; prev layer's bias+relu fused into input ----------
__global__ void k_mmh(const float* __restrict__ in, const void* __restrict__ bias, int do_relu,
                      const void* __restrict__ W, const int* __restrict__ flags,
                      const float* __restrict__ dinv, int mul_dinv,
                      float* __restrict__ out, int N){
  __shared__ float Ws[32*32];
  __shared__ float xs[32*32];
  int tid = threadIdx.x;
  int f32 = flags[0];
  for (int i = tid; i < 1024; i += 256) Ws[i] = ldf(W, i, f32);
  int n0 = blockIdx.x*32;
  for (int i = tid; i < 1024; i += 256){
    int r = i >> 5, k = i & 31, n = n0 + r;
    float v = 0.f;
    if (n < N){
      v = in[n*32+k] + ldf(bias, k, f32);
      if (do_relu) v = fmaxf(v, 0.f);
    }
    xs[i] = v;
  }
  __syncthreads();
  int f = tid & 31, r = tid >> 5;
  float a0=0.f, a1=0.f, a2=0.f, a3=0.f;
  for (int k = 0; k < 32; ++k){
    float w = Ws[k*32+f];
    a0 = fmaf(xs[(r    )*32+k], w, a0);
    a1 = fmaf(xs[(r+ 8)*32+k], w, a1);
    a2 = fmaf(xs[(r+16)*32+k], w, a2);
    a3 = fmaf(xs[(r+24)*32+k], w, a3);
  }
  int n;
  n = n0+r;    if (n < N) out[n*32+f] = mul_dinv ? a0*dinv[n] : a0;
  n = n0+r+8;  if (n < N) out[n*32+f] = mul_dinv ? a1*dinv[n] : a1;
  n = n0+r+16; if (n < N) out[n*32+f] = mul_dinv ? a2*dinv[n] : a2;
  n = n0+r+24; if (n < N) out[n*32+f] = mul_dinv ? a3*dinv[n] : a3;
}

// ---------- mean pool per graph (batch sorted) ----------
__device__ __forceinline__ int lower_bound_i(const void* __restrict__ a, int n, int v, int i64){
  int lo = 0, hi = n;
  while (lo < hi){ int mid = (lo+hi) >> 1; if (ldi(a, mid, i64) < v) lo = mid+1; else hi = mid; }
  return lo;
}

__global__ void k_pool(const float* __restrict__ agg, const void* __restrict__ b3,
                       const void* __restrict__ batch, const int* __restrict__ flags,
                       float* __restrict__ gpool, int N){
  int f32 = flags[0], i64 = flags[1];
  int g = blockIdx.x;
  int start = lower_bound_i(batch, N, g, i64);
  int end   = lower_bound_i(batch, N, g+1, i64);
  int tid = threadIdx.x;
  int f = tid & 31, r = tid >> 5;
  float acc = 0.f;
  for (int n = start + r; n < end; n += 8) acc += agg[n*32+f];
  __shared__ float red[8][32];
  red[r][f] = acc;
  __syncthreads();
  if (r == 0){
    float s = red[0][f];
    #pragma unroll
    for (int j = 1; j < 8; ++j) s += red[j][f];
    int c = end - start;
    float gv = (c > 0) ? (s / (float)c + ldf(b3, f, f32)) : 0.f;
    gpool[g*32+f] = gv;
  }
}

// ---------- MLP head: 1 block, column-per-thread, 16 row-accumulators (ILP) ----------
__global__ void __launch_bounds__(256, 1) k_mlp(const float* __restrict__ gpool,
                      const void* __restrict__ L1w, const void* __restrict__ L1b,
                      const void* __restrict__ L2w, const void* __restrict__ L2b,
                      const void* __restrict__ L3w, const void* __restrict__ L3b,
                      const void* __restrict__ L4w, const void* __restrict__ L4b,
                      const int* __restrict__ flags, void* __restrict__ out){
  __shared__ float gin[64*32];
  __shared__ float A[64*65];
  __shared__ float B[64*65];
  __shared__ float ws[64*64];
  __shared__ float wb[64];
  int tid = threadIdx.x;
  int f32 = flags[0];
  int j  = tid & 63;
  int i0 = tid >> 6;
  float acc[16];

  for (int i = tid; i < 64*32; i += 256) gin[i] = gpool[i];
  for (int i = tid; i < 2048; i += 256) ws[i] = ldf(L1w, i, f32);
  if (tid < 64) wb[tid] = ldf(L1b, tid, f32);
  __syncthreads();
  #pragma unroll
  for (int r = 0; r < 16; ++r) acc[r] = wb[j];
  for (int k = 0; k < 32; ++k){
    float w = ws[k*64+j];
    #pragma unroll
    for (int r = 0; r < 16; ++r) acc[r] = fmaf(gin[(i0+4*r)*32+k], w, acc[r]);
  }
  #pragma unroll
  for (int r = 0; r < 16; ++r) A[(i0+4*r)*65+j] = fmaxf(acc[r], 0.f);
  __syncthreads();
  for (int i = tid; i < 4096; i += 256) ws[i] = ldf(L2w, i, f32);
  if (tid < 64) wb[tid] = ldf(L2b, tid, f32);
  __syncthreads();
  #pragma unroll
  for (int r = 0; r < 16; ++r) acc[r] = wb[j];
  for (int k = 0; k < 64; ++k){
    float w = ws[k*64+j];
    #pragma unroll
    for (int r = 0; r < 16; ++r) acc[r] = fmaf(A[(i0+4*r)*65+k], w, acc[r]);
  }
  #pragma unroll
  for (int r = 0; r < 16; ++r) B[(i0+4*r)*65+j] = fmaxf(acc[r], 0.f);
  __syncthreads();
  for (int i = tid; i < 4096; i += 256) ws[i] = ldf(L3w, i, f32);
  if (tid < 64) wb[tid] = ldf(L3b, tid, f32);
  __syncthreads();
  #pragma unroll
  for (int r = 0; r < 16; ++r) acc[r] = wb[j];
  for (int k = 0; k < 64; ++k){
    float w = ws[k*64+j];
    #pragma unroll
    for (int r = 0; r < 16; ++r) acc[r] = fmaf(B[(i0+4*r)*65+k], w, acc[r]);
  }
  #pragma unroll
  for (int r = 0; r < 16; ++r) A[(i0+4*r)*65+j] = fmaxf(acc[r], 0.f);
  __syncthreads();
  for (int i = tid; i < 640; i += 256) ws[i] = ldf(L4w, i, f32);
  if (tid < 10) wb[tid] = ldf(L4b, tid, f32);
  __syncthreads();
  if (tid < 64){
    int row = tid;
    float a10[10];
    #pragma unroll
    for (int c = 0; c < 10; ++c) a10[c] = wb[c];
    for (int k = 0; k < 64; ++k){
      float av = A[row*65+k];
      #pragma unroll
      for (int c = 0; c < 10; ++c) a10[c] = fmaf(av, ws[k*10+c], a10[c]);
    }
    #pragma unroll
    for (int c = 0; c < 10; ++c){
      if (f32) ((float*)out)[row*10+c] = a10[c];
      else     ((bf16*)out)[row*10+c]  = __float2bfloat16(a10[c]);
    }
  }
}

// ---------- fallback (atomic-scatter path, small ws) ----------
__global__ void k_init_deg(float* __restrict__ deg, int N){
  int i = blockIdx.x*256 + threadIdx.x;
  if (i < N) deg[i] = 1.0f;
}
__global__ void k_deg_accum(const void* __restrict__ eidx, long long E,
                            const void* __restrict__ w, const int* __restrict__ flags,
                            float* __restrict__ deg){
  long long e = (long long)blockIdx.x*256 + threadIdx.x;
  if (e < E){
    int f32 = flags[0], i64 = flags[1];
    atomicAdd(&deg[ldi(eidx, E + e, i64)], ldf(w, e, f32));
  }
}
__global__ void k_dinv(float* __restrict__ deg, int N){
  int i = blockIdx.x*256 + threadIdx.x;
  if (i < N){
    float d = deg[i];
    deg[i] = (d > 0.f) ? rsqrtf(fmaxf(d, 1e-30f)) : 0.f;
  }
}
__global__ void k_norm(const void* __restrict__ eidx, long long E,
                       const void* __restrict__ w, const float* __restrict__ dinv,
                       const int* __restrict__ flags, float* __restrict__ nrm){
  long long e = (long long)blockIdx.x*256 + threadIdx.x;
  if (e < E){
    int f32 = flags[0], i64 = flags[1];
    int s = ldi(eidx, e, i64), d = ldi(eidx, E + e, i64);
    nrm[e] = dinv[s] * ldf(w, e, f32) * dinv[d];
  }
}
__global__ void k_selfloop(const float* __restrict__ hlin, const float* __restrict__ dinv,
                           float* __restrict__ agg, int N){
  int idx = blockIdx.x*256 + threadIdx.x;
  if (idx < N*32){
    int n = idx >> 5;
    float di = dinv[n];
    agg[idx] = di*di*hlin[idx];
  }
}
__global__ void k_scatter(const void* __restrict__ eidx, long long E,
                          const float* __restrict__ nrm, const int* __restrict__ flags,
                          const float* __restrict__ hlin, float* __restrict__ agg){
  long long idx = (long long)blockIdx.x*256 + threadIdx.x;
  if (idx < E*32){
    int i64 = flags[1];
    long long e = idx >> 5;
    int f = (int)(idx & 31);
    int s = ldi(eidx, e, i64), d = ldi(eidx, E + e, i64);
    atomicAdd(&agg[(long long)d*32 + f], nrm[e] * hlin[(long long)s*32 + f]);
  }
}

extern "C" void kernel_launch(void* const* d_in, const int* in_sizes, int n_in,
                              void* d_out, int out_size, void* d_ws, size_t ws_size,
                              hipStream_t stream){
  const void* x   = d_in[0];
  const void* ew  = d_in[1];
  const void* W1  = d_in[2];
  const void* b1  = d_in[3];
  const void* W2  = d_in[4];
  const void* b2  = d_in[5];
  const void* W3  = d_in[6];
  const void* b3  = d_in[7];
  const void* L1w = d_in[8];  const void* L1b = d_in[9];
  const void* L2w = d_in[10]; const void* L2b = d_in[11];
  const void* L3w = d_in[12]; const void* L3b = d_in[13];
  const void* L4w = d_in[14]; const void* L4b = d_in[15];
  const void* eidx  = d_in[16];
  const void* batch = d_in[17];
  const long long E = in_sizes[1];
  const int N = in_sizes[17];

  dim3 b(256);
  int gN   = (N + 255)/256;
  int gE   = (int)((E + 255)/256);
  int gMM  = (N + 31)/32;
  int gNd4 = (N + 3)/4;
  int gBH  = (int)((E + 4095)/4096);
  int gBN  = (int)((E + BINCH - 1)/BINCH);

  const int shift = 8;                       // 256-node buckets
  int NB = (N + 255) >> 8;

  auto AL = [](size_t v){ return (v + 255) & ~(size_t)255; };

  char* base = (char*)d_ws;
  size_t off = 0;
  size_t o_flags = off; off += AL(64*4);
  size_t o_rowp  = off; off += AL((size_t)(N+1)*4);
  size_t o_dinv  = off; off += AL((size_t)N*4);
  size_t o_bbase = off; off += AL((size_t)(NB+1)*4);
  size_t o_bcnt  = off; off += AL((size_t)NB*4) + AL((size_t)NB*4);   // bcnt + gcur
  size_t o_csr   = off; off += AL((size_t)E*8);
  size_t o_tmp   = off; off += AL((size_t)E*8);
  size_t o_bufA  = off; off += AL((size_t)N*128);
  size_t o_bufB  = off; off += AL((size_t)N*128);
  size_t o_gp    = off; off += AL(2048*4);
  size_t needed  = off;

  if (ws_size >= needed && NB <= 512 && N < (1<<24)){
    int*   flags  = (int*)(base + o_flags);
    int*   rowptr = (int*)(base + o_rowp);
    float* dinv   = (float*)(base + o_dinv);
    int*   bbase  = (int*)(base + o_bbase);
    int*   bcnt   = (int*)(base + o_bcnt);
    int*   gcur   = (int*)(base + o_bcnt + AL((size_t)NB*4));
    int2*  csr    = (int2*)(base + o_csr);
    int2*  csrTmp = (int2*)(base + o_tmp);
    float* bufA   = (float*)(base + o_bufA);
    float* bufB   = (float*)(base + o_bufB);
    float* gpool  = (float*)(base + o_gp);

    k_sniff <<<1,    b, 0, stream>>>(x, eidx, flags);
    k_zero  <<<(int)((AL((size_t)NB*4)/4 + NB + 255)/256), b, 0, stream>>>(bcnt, (int)(AL((size_t)NB*4)/4 + NB));
    k_bhist <<<gBH,  b, 0, stream>>>(eidx, E, flags, shift, NB, bcnt);
    k_bscan <<<1,    b, 0, stream>>>(bcnt, bbase, NB, (int)E);
    k_bin   <<<gBN,  b, 0, stream>>>(eidx, E, ew, flags, shift, NB, bbase, gcur, csrTmp);
    k_bucket<<<NB,   b, 0, stream>>>(csrTmp, bbase, shift, N, (int)E, csr, rowptr, dinv);
    // layer 1
    k_mm1   <<<gMM,  b, 0, stream>>>(x, W1, flags, dinv, 1, bufA, N);
    k_pull  <<<gNd4, b, 0, stream>>>(csr, rowptr, dinv, bufA, bufB, N);
    // layer 2
    k_mmh   <<<gMM,  b, 0, stream>>>(bufB, b1, 1, W2, flags, dinv, 1, bufA, N);
    k_pull  <<<gNd4, b, 0, stream>>>(csr, rowptr, dinv, bufA, bufB, N);
    // layer 3
    k_mmh   <<<gMM,  b, 0, stream>>>(bufB, b2, 1, W3, flags, dinv, 1, bufA, N);
    k_pull  <<<gNd4, b, 0, stream>>>(csr, rowptr, dinv, bufA, bufB, N);
    // head
    k_pool<<<64, b, 0, stream>>>(bufB, b3, batch, flags, gpool, N);
    k_mlp <<<1,  b, 0, stream>>>(gpool, L1w, L1b, L2w, L2b, L3w, L3b, L4w, L4b, flags, d_out);
    return;
  }

  // ---- fallback: atomic-scatter path ----
  {
    float* wf    = (float*)d_ws;
    int*   flags = (int*)d_ws;
    size_t Npad  = ((size_t)N + 255) & ~(size_t)255;
    float* dinv  = wf + 64;
    float* nrm   = dinv + Npad;
    float* bufA  = nrm + E;
    float* bufB  = bufA + (size_t)N*32;
    float* gpool = bufB + (size_t)N*32;
    int gN32 = (N*32 + 255)/256;
    int gE32 = (int)((E*32 + 255)/256);

    k_sniff    <<<1,    b, 0, stream>>>(x, eidx, flags);
    k_init_deg <<<gN,   b, 0, stream>>>(dinv, N);
    k_deg_accum<<<gE,   b, 0, stream>>>(eidx, E, ew, flags, dinv);
    k_dinv     <<<gN,   b, 0, stream>>>(dinv, N);
    k_norm     <<<gE,   b, 0, stream>>>(eidx, E, ew, dinv, flags, nrm);
    k_mm1      <<<gMM,  b, 0, stream>>>(x, W1, flags, dinv, 0, bufA, N);
    k_selfloop <<<gN32, b, 0, stream>>>(bufA, dinv, bufB, N);
    k_scatter  <<<gE32, b, 0, stream>>>(eidx, E, nrm, flags, bufA, bufB);
    k_mmh      <<<gMM,  b, 0, stream>>>(bufB, b1, 1, W2, flags, dinv, 0, bufA, N);
    k_selfloop <<<gN32, b, 0, stream>>>(bufA, dinv, bufB, N);
    k_scatter  <<<gE32, b, 0, stream>>>(eidx, E, nrm, flags, bufA, bufB);
    k_mmh      <<<gMM,  b, 0, stream>>>(bufB, b2, 1, W3, flags, dinv, 0, bufA, N);
    k_selfloop <<<gN32, b, 0, stream>>>(bufA, dinv, bufB, N);
    k_scatter  <<<gE32, b, 0, stream>>>(eidx, E, nrm, flags, bufA, bufB);
    k_pool<<<64, b, 0, stream>>>(bufB, b3, batch, flags, gpool, N);
    k_mlp <<<1,  b, 0, stream>>>(gpool, L1w, L1b, L2w, L2b, L3w, L3b, L4w, L4b, flags, d_out);
  }
}

// Round 10
// 641.970 us; speedup vs baseline: 4.0488x; 1.0681x over previous
//
#include <hip/hip_runtime.h>
#include <hip/hip_bf16.h>

typedef __hip_bfloat16 bf16;

// ---------- dtype-adaptive loads (flags are wave-uniform) ----------
__device__ __forceinline__ float ldf(const void* p, long long i, int f32){
  return f32 ? ((const float*)p)[i] : __bfloat162float(((const bf16*)p)[i]);
}
__device__ __forceinline__ int ldi(const void* p, long long i, int i64){
  return i64 ? (int)((const long long*)p)[i] : ((const int*)p)[i];
}

// ---------- sniff input dtypes once per launch ----------
__global__ void k_sniff(const void* __restrict__ x, const void* __restrict__ eidx,
                        int* __restrict__ flags){
  __shared__ int s_f, s_i;
  if (threadIdx.x == 0){ s_f = 0; s_i = 0; }
  __syncthreads();
  int t = threadIdx.x;
  const unsigned short* u = (const unsigned short*)x;
  int hits = 0;
  for (int k = t; k < 2048; k += 256){
    unsigned short v = u[2*k];
    int e = (v >> 7) & 0xFF;
    if (e == 0xFF || e == 0x00) hits++;
  }
  if (hits) atomicAdd(&s_f, 1);
  const int* ii = (const int*)eidx;
  int nz = 0;
  for (int k = t; k < 1024; k += 256){ if (ii[2*k+1] != 0) nz++; }
  if (nz) atomicAdd(&s_i, 1);
  __syncthreads();
  if (threadIdx.x == 0){
    flags[0] = s_f ? 1 : 0;   // 1 = float32, 0 = bf16
    flags[1] = s_i ? 0 : 1;   // 1 = int64,   0 = int32
  }
}

__global__ void k_zero(int* __restrict__ p, int n){
  int i = blockIdx.x*256 + threadIdx.x;
  if (i < n) p[i] = 0;
}

// ================= binned CSR build (shift=8: 256-node buckets) =================

__global__ void __launch_bounds__(256) k_bhist(const void* __restrict__ eidx, long long E,
                       const int* __restrict__ flags, int shift, int NB,
                       int* __restrict__ bcnt){
  __shared__ int h[1024];
  int t = threadIdx.x;
  for (int b = t; b < NB; b += 256) h[b] = 0;
  __syncthreads();
  int i64 = flags[1];
  long long e0 = (long long)blockIdx.x*4096;
  long long e1 = e0 + 4096; if (e1 > E) e1 = E;
  for (long long e = e0 + t; e < e1; e += 256){
    int d = ldi(eidx, E + e, i64);
    atomicAdd(&h[d >> shift], 1);
  }
  __syncthreads();
  for (int b = t; b < NB; b += 256) if (h[b]) atomicAdd(&bcnt[b], h[b]);
}

__global__ void __launch_bounds__(256) k_bscan(const int* __restrict__ bcnt, int* __restrict__ bbase,
                       int NB, int E){
  __shared__ int tmp[256];
  int t = threadIdx.x;
  int v0 = (4*t+0 < NB) ? bcnt[4*t+0] : 0;
  int v1 = (4*t+1 < NB) ? bcnt[4*t+1] : 0;
  int v2 = (4*t+2 < NB) ? bcnt[4*t+2] : 0;
  int v3 = (4*t+3 < NB) ? bcnt[4*t+3] : 0;
  int s = v0+v1+v2+v3;
  tmp[t] = s;
  __syncthreads();
  for (int st = 1; st < 256; st <<= 1){
    int add = (t >= st) ? tmp[t-st] : 0;
    __syncthreads();
    tmp[t] += add;
    __syncthreads();
  }
  int run = tmp[t] - s;
  if (4*t+0 < NB){ bbase[4*t+0] = run; run += v0; }
  if (4*t+1 < NB){ bbase[4*t+1] = run; run += v1; }
  if (4*t+2 < NB){ bbase[4*t+2] = run; run += v2; }
  if (4*t+3 < NB){ bbase[4*t+3] = run; run += v3; }
  if (t == 255) bbase[NB] = E;
}

// 4096-edge chunks, 512 threads (8 waves, 3 blocks/CU -> 24 waves/CU)
#define BINCH 4096
__global__ void __launch_bounds__(512) k_bin(const void* __restrict__ eidx, long long E,
                     const void* __restrict__ ew, const int* __restrict__ flags,
                     int shift, int NB, const int* __restrict__ bbase,
                     int* __restrict__ gcur, int2* __restrict__ csrTmp){
  __shared__ int bst[512];
  __shared__ int bcur[512];
  __shared__ int gof[512];
  __shared__ int tmp[512];
  __shared__ int2 ent[BINCH];
  __shared__ unsigned short entb[BINCH];
  int t = threadIdx.x;
  int i64 = flags[1], f32 = flags[0];
  long long e0 = (long long)blockIdx.x*BINCH;
  int cnt = (int)(((E - e0) < BINCH) ? (E - e0) : BINCH);
  int msk = (1 << shift) - 1;
  for (int b = t; b < NB; b += 512) bst[b] = 0;
  __syncthreads();
  for (int i = t; i < cnt; i += 512){
    int d = ldi(eidx, E + e0 + i, i64);
    atomicAdd(&bst[d >> shift], 1);
  }
  __syncthreads();
  int v = (t < NB) ? bst[t] : 0;
  tmp[t] = v;
  __syncthreads();
  for (int st = 1; st < 512; st <<= 1){
    int add = (t >= st) ? tmp[t-st] : 0;
    __syncthreads();
    tmp[t] += add;
    __syncthreads();
  }
  int run = tmp[t] - v;
  __syncthreads();
  if (t < NB){
    bst[t] = run; bcur[t] = run;
    if (v) gof[t] = atomicAdd(&gcur[t], v);
  }
  __syncthreads();
  for (int i = t; i < cnt; i += 512){
    int d  = ldi(eidx, E + e0 + i, i64);
    int sc = ldi(eidx, e0 + i, i64);
    float w = ldf(ew, e0 + i, f32);
    int b = d >> shift;
    int dl = d & msk;
    int pos = atomicAdd(&bcur[b], 1);
    ent[pos]  = make_int2((dl << 24) | sc, __float_as_int(w));
    entb[pos] = (unsigned short)b;
  }
  __syncthreads();
  for (int i = t; i < cnt; i += 512){
    int b = entb[i];
    int gpos = bbase[b] + gof[b] + (i - bst[b]);
    csrTmp[gpos] = ent[i];
  }
}

// per-bucket (1024 threads): counting sort by dst-low; deg/dinv/rowptr in-pass; csr.y = w*dinv[dst]
__global__ void __launch_bounds__(1024) k_bucket(const int2* __restrict__ csrTmp, const int* __restrict__ bbase,
                        int shift, int N, int E, int2* __restrict__ csr,
                        int* __restrict__ rowptr, float* __restrict__ dinv){
  __shared__ int   h[256];
  __shared__ int   st[256];
  __shared__ int   cur[256];
  __shared__ float wsum[256];
  __shared__ float sdv[256];
  int b = blockIdx.x, t = threadIdx.x;
  int base = bbase[b], cnt = bbase[b+1] - base;
  if (t < 256){ h[t] = 0; wsum[t] = 0.f; }
  __syncthreads();
  for (int i = t; i < cnt; i += 1024){
    int2 p = csrTmp[base + i];
    int dl = ((unsigned)p.x) >> 24;
    atomicAdd(&h[dl], 1);
    atomicAdd(&wsum[dl], __int_as_float(p.y));
  }
  __syncthreads();
  int c = (t < 256) ? h[t] : 0;
  if (t < 256) st[t] = c;
  __syncthreads();
  for (int s2 = 1; s2 < 256; s2 <<= 1){
    int add = (t >= s2 && t < 256) ? st[t-s2] : 0;
    __syncthreads();
    if (t < 256) st[t] += add;
    __syncthreads();
  }
  if (t < 256){
    int ex = st[t] - c;
    cur[t] = ex;
    int n = (b << shift) + t;
    if (n < N){
      float deg = 1.f + wsum[t];
      float di = (deg > 0.f) ? rsqrtf(fmaxf(deg, 1e-30f)) : 0.f;
      sdv[t] = di;
      dinv[n] = di;
      rowptr[n] = base + ex;
      if (n == N-1) rowptr[N] = E;
    }
  }
  __syncthreads();
  for (int i = t; i < cnt; i += 1024){
    int2 p = csrTmp[base + i];
    int dl = ((unsigned)p.x) >> 24;
    int pos = atomicAdd(&cur[dl], 1);
    float nm = __int_as_float(p.y) * sdv[dl];       // w * dinv[dst]
    csr[base + pos] = make_int2(p.x & 0xFFFFFF, __float_as_int(nm));
  }
}

// ---------- pull: wave/node, 2-way unrolled ----------
// zp = dinv*(hW); agg[n] = dinv[n]*zp[n] + sum csr.y*zp[src]
__global__ void k_pull(const int2* __restrict__ csr, const int* __restrict__ rowptr,
                       const float* __restrict__ dinv, const float* __restrict__ zp,
                       float* __restrict__ agg, int N){
  int n = blockIdx.x*4 + (threadIdx.x >> 6);
  int lane = threadIdx.x & 63;
  if (n >= N) return;
  int g = lane >> 3;            // edge subgroup 0..7
  int q = lane & 7;             // feature quad 0..7
  const float4* h4 = (const float4*)zp;
  int s0 = rowptr[n], s1 = rowptr[n+1];
  float4 acc = make_float4(0.f,0.f,0.f,0.f);
  if (g == 0){
    float di = dinv[n];
    float4 hv = h4[(long long)n*8 + q];
    acc.x = di*hv.x; acc.y = di*hv.y; acc.z = di*hv.z; acc.w = di*hv.w;
  }
  int j = s0 + g;
  for (; j + 8 < s1; j += 16){
    int2 p0 = csr[j];
    int2 p1 = csr[j+8];
    float nm0 = __int_as_float(p0.y);
    float nm1 = __int_as_float(p1.y);
    float4 h0 = h4[(long long)p0.x*8 + q];
    float4 h1 = h4[(long long)p1.x*8 + q];
    acc.x = fmaf(nm0, h0.x, acc.x); acc.y = fmaf(nm0, h0.y, acc.y);
    acc.z = fmaf(nm0, h0.z, acc.z); acc.w = fmaf(nm0, h0.w, acc.w);
    acc.x = fmaf(nm1, h1.x, acc.x); acc.y = fmaf(nm1, h1.y, acc.y);
    acc.z = fmaf(nm1, h1.z, acc.z); acc.w = fmaf(nm1, h1.w, acc.w);
  }
  if (j < s1){
    int2 p = csr[j];
    float nm = __int_as_float(p.y);
    float4 hv = h4[(long long)p.x*8 + q];
    acc.x = fmaf(nm, hv.x, acc.x); acc.y = fmaf(nm, hv.y, acc.y);
    acc.z = fmaf(nm, hv.z, acc.z); acc.w = fmaf(nm, hv.w, acc.w);
  }
  #pragma unroll
  for (int st = 8; st < 64; st <<= 1){
    acc.x += __shfl_xor(acc.x, st, 64);
    acc.y += __shfl_xor(acc.y, st, 64);
    acc.z += __shfl_xor(acc.z, st, 64);
    acc.w += __shfl_xor(acc.w, st, 64);
  }
  if (g == 0) ((float4*)agg)[(long long)n*8 + q] = acc;
}

// ---------- layer-1 matmul: 32 rows/block, 4 outputs/thread; K=128, F=32 ----------
__global__ void k_mm1(const void* __restrict__ x, const void* __restrict__ W,
                      const int* __restrict__ flags, const float* __restrict__ dinv,
                      int mul_dinv, float* __restrict__ out, int N){
  __shared__ float Ws[128*32];
  __shared__ float xs[32*128];
  int tid = threadIdx.x;
  int f32 = flags[0];
  for (int i = tid; i < 4096; i += 256) Ws[i] = ldf(W, i, f32);
  int n0 = blockIdx.x*32;
  for (int i = tid; i < 4096; i += 256){
    int r = i >> 7, k = i & 127, n = n0 + r;
    xs[i] = (n < N) ? ldf(x, (long long)n*128 + k, f32) : 0.f;
  }
  __syncthreads();
  int f = tid & 31, r = tid >> 5;
  float a0=0.f, a1=0.f, a2=0.f, a3=0.f;
  for (int k = 0; k < 128; ++k){
    float w = Ws[k*32+f];
    a0 = fmaf(xs[(r    )*128+k], w, a0);
    a1 = fmaf(xs[(r+ 8)*128+k], w, a1);
    a2 = fmaf(xs[(r+16)*128+k], w, a2);
    a3 = fmaf(xs[(r+24)*128+k], w, a3);
  }
  int n;
  n = n0+r;    if (n < N) out[n*32+f] = mul_dinv ? a0*dinv[n] : a0;
  n = n0+r+8;  if (n < N) out[n*32+f] = mul_dinv ? a1*dinv[n] : a1;
  n = n0+r+16; if (n < N) out[n*32+f] = mul_dinv ? a2*dinv[n] : a2;
  n = n0+r+24; if (n < N) out[n*32+f] = mul_dinv ? a3*dinv[n] : a3;
}

// ---------- hidden matmul: 32 rows/block; prev layer's bias+relu fused into input ----------
__global__ void k_mmh(const float* __restrict__ in, const void* __restrict__ bias, int do_relu,
                      const void* __restrict__ W, const int* __restrict__ flags,
                      const float* __restrict__ dinv, int mul_dinv,
                      float* __restrict__ out, int N){
  __shared__ float Ws[32*32];
  __shared__ float xs[32*32];
  int tid = threadIdx.x;
  int f32 = flags[0];
  for (int i = tid; i < 1024; i += 256) Ws[i] = ldf(W, i, f32);
  int n0 = blockIdx.x*32;
  for (int i = tid; i < 1024; i += 256){
    int r = i >> 5, k = i & 31, n = n0 + r;
    float v = 0.f;
    if (n < N){
      v = in[n*32+k] + ldf(bias, k, f32);
      if (do_relu) v = fmaxf(v, 0.f);
    }
    xs[i] = v;
  }
  __syncthreads();
  int f = tid & 31, r = tid >> 5;
  float a0=0.f, a1=0.f, a2=0.f, a3=0.f;
  for (int k = 0; k < 32; ++k){
    float w = Ws[k*32+f];
    a0 = fmaf(xs[(r    )*32+k], w, a0);
    a1 = fmaf(xs[(r+ 8)*32+k], w, a1);
    a2 = fmaf(xs[(r+16)*32+k], w, a2);
    a3 = fmaf(xs[(r+24)*32+k], w, a3);
  }
  int n;
  n = n0+r;    if (n < N) out[n*32+f] = mul_dinv ? a0*dinv[n] : a0;
  n = n0+r+8;  if (n < N) out[n*32+f] = mul_dinv ? a1*dinv[n] : a1;
  n = n0+r+16; if (n < N) out[n*32+f] = mul_dinv ? a2*dinv[n] : a2;
  n = n0+r+24; if (n < N) out[n*32+f] = mul_dinv ? a3*dinv[n] : a3;
}

// ---------- mean pool per graph (batch sorted) ----------
__device__ __forceinline__ int lower_bound_i(const void* __restrict__ a, int n, int v, int i64){
  int lo = 0, hi = n;
  while (lo < hi){ int mid = (lo+hi) >> 1; if (ldi(a, mid, i64) < v) lo = mid+1; else hi = mid; }
  return lo;
}

__global__ void k_pool(const float* __restrict__ agg, const void* __restrict__ b3,
                       const void* __restrict__ batch, const int* __restrict__ flags,
                       float* __restrict__ gpool, int N){
  int f32 = flags[0], i64 = flags[1];
  int g = blockIdx.x;
  int start = lower_bound_i(batch, N, g, i64);
  int end   = lower_bound_i(batch, N, g+1, i64);
  int tid = threadIdx.x;
  int f = tid & 31, r = tid >> 5;
  float acc = 0.f;
  for (int n = start + r; n < end; n += 8) acc += agg[n*32+f];
  __shared__ float red[8][32];
  red[r][f] = acc;
  __syncthreads();
  if (r == 0){
    float s = red[0][f];
    #pragma unroll
    for (int j = 1; j < 8; ++j) s += red[j][f];
    int c = end - start;
    float gv = (c > 0) ? (s / (float)c + ldf(b3, f, f32)) : 0.f;
    gpool[g*32+f] = gv;
  }
}

// ---------- MLP head: 1 block, column-per-thread, 16 row-accumulators (ILP) ----------
__global__ void __launch_bounds__(256, 1) k_mlp(const float* __restrict__ gpool,
                      const void* __restrict__ L1w, const void* __restrict__ L1b,
                      const void* __restrict__ L2w, const void* __restrict__ L2b,
                      const void* __restrict__ L3w, const void* __restrict__ L3b,
                      const void* __restrict__ L4w, const void* __restrict__ L4b,
                      const int* __restrict__ flags, void* __restrict__ out){
  __shared__ float gin[64*32];
  __shared__ float A[64*65];
  __shared__ float B[64*65];
  __shared__ float ws[64*64];
  __shared__ float wb[64];
  int tid = threadIdx.x;
  int f32 = flags[0];
  int j  = tid & 63;
  int i0 = tid >> 6;
  float acc[16];

  for (int i = tid; i < 64*32; i += 256) gin[i] = gpool[i];
  for (int i = tid; i < 2048; i += 256) ws[i] = ldf(L1w, i, f32);
  if (tid < 64) wb[tid] = ldf(L1b, tid, f32);
  __syncthreads();
  #pragma unroll
  for (int r = 0; r < 16; ++r) acc[r] = wb[j];
  for (int k = 0; k < 32; ++k){
    float w = ws[k*64+j];
    #pragma unroll
    for (int r = 0; r < 16; ++r) acc[r] = fmaf(gin[(i0+4*r)*32+k], w, acc[r]);
  }
  #pragma unroll
  for (int r = 0; r < 16; ++r) A[(i0+4*r)*65+j] = fmaxf(acc[r], 0.f);
  __syncthreads();
  for (int i = tid; i < 4096; i += 256) ws[i] = ldf(L2w, i, f32);
  if (tid < 64) wb[tid] = ldf(L2b, tid, f32);
  __syncthreads();
  #pragma unroll
  for (int r = 0; r < 16; ++r) acc[r] = wb[j];
  for (int k = 0; k < 64; ++k){
    float w = ws[k*64+j];
    #pragma unroll
    for (int r = 0; r < 16; ++r) acc[r] = fmaf(A[(i0+4*r)*65+k], w, acc[r]);
  }
  #pragma unroll
  for (int r = 0; r < 16; ++r) B[(i0+4*r)*65+j] = fmaxf(acc[r], 0.f);
  __syncthreads();
  for (int i = tid; i < 4096; i += 256) ws[i] = ldf(L3w, i, f32);
  if (tid < 64) wb[tid] = ldf(L3b, tid, f32);
  __syncthreads();
  #pragma unroll
  for (int r = 0; r < 16; ++r) acc[r] = wb[j];
  for (int k = 0; k < 64; ++k){
    float w = ws[k*64+j];
    #pragma unroll
    for (int r = 0; r < 16; ++r) acc[r] = fmaf(B[(i0+4*r)*65+k], w, acc[r]);
  }
  #pragma unroll
  for (int r = 0; r < 16; ++r) A[(i0+4*r)*65+j] = fmaxf(acc[r], 0.f);
  __syncthreads();
  for (int i = tid; i < 640; i += 256) ws[i] = ldf(L4w, i, f32);
  if (tid < 10) wb[tid] = ldf(L4b, tid, f32);
  __syncthreads();
  if (tid < 64){
    int row = tid;
    float a10[10];
    #pragma unroll
    for (int c = 0; c < 10; ++c) a10[c] = wb[c];
    for (int k = 0; k < 64; ++k){
      float av = A[row*65+k];
      #pragma unroll
      for (int c = 0; c < 10; ++c) a10[c] = fmaf(av, ws[k*10+c], a10[c]);
    }
    #pragma unroll
    for (int c = 0; c < 10; ++c){
      if (f32) ((float*)out)[row*10+c] = a10[c];
      else     ((bf16*)out)[row*10+c]  = __float2bfloat16(a10[c]);
    }
  }
}

// ---------- fallback (atomic-scatter path, small ws) ----------
__global__ void k_init_deg(float* __restrict__ deg, int N){
  int i = blockIdx.x*256 + threadIdx.x;
  if (i < N) deg[i] = 1.0f;
}
__global__ void k_deg_accum(const void* __restrict__ eidx, long long E,
                            const void* __restrict__ w, const int* __restrict__ flags,
                            float* __restrict__ deg){
  long long e = (long long)blockIdx.x*256 + threadIdx.x;
  if (e < E){
    int f32 = flags[0], i64 = flags[1];
    atomicAdd(&deg[ldi(eidx, E + e, i64)], ldf(w, e, f32));
  }
}
__global__ void k_dinv(float* __restrict__ deg, int N){
  int i = blockIdx.x*256 + threadIdx.x;
  if (i < N){
    float d = deg[i];
    deg[i] = (d > 0.f) ? rsqrtf(fmaxf(d, 1e-30f)) : 0.f;
  }
}
__global__ void k_norm(const void* __restrict__ eidx, long long E,
                       const void* __restrict__ w, const float* __restrict__ dinv,
                       const int* __restrict__ flags, float* __restrict__ nrm){
  long long e = (long long)blockIdx.x*256 + threadIdx.x;
  if (e < E){
    int f32 = flags[0], i64 = flags[1];
    int s = ldi(eidx, e, i64), d = ldi(eidx, E + e, i64);
    nrm[e] = dinv[s] * ldf(w, e, f32) * dinv[d];
  }
}
__global__ void k_selfloop(const float* __restrict__ hlin, const float* __restrict__ dinv,
                           float* __restrict__ agg, int N){
  int idx = blockIdx.x*256 + threadIdx.x;
  if (idx < N*32){
    int n = idx >> 5;
    float di = dinv[n];
    agg[idx] = di*di*hlin[idx];
  }
}
__global__ void k_scatter(const void* __restrict__ eidx, long long E,
                          const float* __restrict__ nrm, const int* __restrict__ flags,
                          const float* __restrict__ hlin, float* __restrict__ agg){
  long long idx = (long long)blockIdx.x*256 + threadIdx.x;
  if (idx < E*32){
    int i64 = flags[1];
    long long e = idx >> 5;
    int f = (int)(idx & 31);
    int s = ldi(eidx, e, i64), d = ldi(eidx, E + e, i64);
    atomicAdd(&agg[(long long)d*32 + f], nrm[e] * hlin[(long long)s*32 + f]);
  }
}

extern "C" void kernel_launch(void* const* d_in, const int* in_sizes, int n_in,
                              void* d_out, int out_size, void* d_ws, size_t ws_size,
                              hipStream_t stream){
  const void* x   = d_in[0];
  const void* ew  = d_in[1];
  const void* W1  = d_in[2];
  const void* b1  = d_in[3];
  const void* W2  = d_in[4];
  const void* b2  = d_in[5];
  const void* W3  = d_in[6];
  const void* b3  = d_in[7];
  const void* L1w = d_in[8];  const void* L1b = d_in[9];
  const void* L2w = d_in[10]; const void* L2b = d_in[11];
  const void* L3w = d_in[12]; const void* L3b = d_in[13];
  const void* L4w = d_in[14]; const void* L4b = d_in[15];
  const void* eidx  = d_in[16];
  const void* batch = d_in[17];
  const long long E = in_sizes[1];
  const int N = in_sizes[17];

  dim3 b(256);
  int gN   = (N + 255)/256;
  int gE   = (int)((E + 255)/256);
  int gMM  = (N + 31)/32;
  int gNd4 = (N + 3)/4;
  int gBH  = (int)((E + 4095)/4096);
  int gBN  = (int)((E + BINCH - 1)/BINCH);

  const int shift = 8;                       // 256-node buckets
  int NB = (N + 255) >> 8;

  auto AL = [](size_t v){ return (v + 255) & ~(size_t)255; };

  char* base = (char*)d_ws;
  size_t off = 0;
  size_t o_flags = off; off += AL(64*4);
  size_t o_rowp  = off; off += AL((size_t)(N+1)*4);
  size_t o_dinv  = off; off += AL((size_t)N*4);
  size_t o_bbase = off; off += AL((size_t)(NB+1)*4);
  size_t o_bcnt  = off; off += AL((size_t)NB*4) + AL((size_t)NB*4);   // bcnt + gcur
  size_t o_csr   = off; off += AL((size_t)E*8);
  size_t o_tmp   = off; off += AL((size_t)E*8);
  size_t o_bufA  = off; off += AL((size_t)N*128);
  size_t o_bufB  = off; off += AL((size_t)N*128);
  size_t o_gp    = off; off += AL(2048*4);
  size_t needed  = off;

  if (ws_size >= needed && NB <= 512 && N < (1<<24)){
    int*   flags  = (int*)(base + o_flags);
    int*   rowptr = (int*)(base + o_rowp);
    float* dinv   = (float*)(base + o_dinv);
    int*   bbase  = (int*)(base + o_bbase);
    int*   bcnt   = (int*)(base + o_bcnt);
    int*   gcur   = (int*)(base + o_bcnt + AL((size_t)NB*4));
    int2*  csr    = (int2*)(base + o_csr);
    int2*  csrTmp = (int2*)(base + o_tmp);
    float* bufA   = (float*)(base + o_bufA);
    float* bufB   = (float*)(base + o_bufB);
    float* gpool  = (float*)(base + o_gp);

    k_sniff <<<1,    b, 0, stream>>>(x, eidx, flags);
    k_zero  <<<(int)((AL((size_t)NB*4)/4 + NB + 255)/256), b, 0, stream>>>(bcnt, (int)(AL((size_t)NB*4)/4 + NB));
    k_bhist <<<gBH,  b, 0, stream>>>(eidx, E, flags, shift, NB, bcnt);
    k_bscan <<<1,    b, 0, stream>>>(bcnt, bbase, NB, (int)E);
    k_bin   <<<gBN,  dim3(512), 0, stream>>>(eidx, E, ew, flags, shift, NB, bbase, gcur, csrTmp);
    k_bucket<<<NB,   dim3(1024), 0, stream>>>(csrTmp, bbase, shift, N, (int)E, csr, rowptr, dinv);
    // layer 1
    k_mm1   <<<gMM,  b, 0, stream>>>(x, W1, flags, dinv, 1, bufA, N);
    k_pull  <<<gNd4, b, 0, stream>>>(csr, rowptr, dinv, bufA, bufB, N);
    // layer 2
    k_mmh   <<<gMM,  b, 0, stream>>>(bufB, b1, 1, W2, flags, dinv, 1, bufA, N);
    k_pull  <<<gNd4, b, 0, stream>>>(csr, rowptr, dinv, bufA, bufB, N);
    // layer 3
    k_mmh   <<<gMM,  b, 0, stream>>>(bufB, b2, 1, W3, flags, dinv, 1, bufA, N);
    k_pull  <<<gNd4, b, 0, stream>>>(csr, rowptr, dinv, bufA, bufB, N);
    // head
    k_pool<<<64, b, 0, stream>>>(bufB, b3, batch, flags, gpool, N);
    k_mlp <<<1,  b, 0, stream>>>(gpool, L1w, L1b, L2w, L2b, L3w, L3b, L4w, L4b, flags, d_out);
    return;
  }

  // ---- fallback: atomic-scatter path ----
  {
    float* wf    = (float*)d_ws;
    int*   flags = (int*)d_ws;
    size_t Npad  = ((size_t)N + 255) & ~(size_t)255;
    float* dinv  = wf + 64;
    float* nrm   = dinv + Npad;
    float* bufA  = nrm + E;
    float* bufB  = bufA + (size_t)N*32;
    float* gpool = bufB + (size_t)N*32;
    int gN32 = (N*32 + 255)/256;
    int gE32 = (int)((E*32 + 255)/256);

    k_sniff    <<<1,    b, 0, stream>>>(x, eidx, flags);
    k_init_deg <<<gN,   b, 0, stream>>>(dinv, N);
    k_deg_accum<<<gE,   b, 0, stream>>>(eidx, E, ew, flags, dinv);
    k_dinv     <<<gN,   b, 0, stream>>>(dinv, N);
    k_norm     <<<gE,   b, 0, stream>>>(eidx, E, ew, dinv, flags, nrm);
    k_mm1      <<<gMM,  b, 0, stream>>>(x, W1, flags, dinv, 0, bufA, N);
    k_selfloop <<<gN32, b, 0, stream>>>(bufA, dinv, bufB, N);
    k_scatter  <<<gE32, b, 0, stream>>>(eidx, E, nrm, flags, bufA, bufB);
    k_mmh      <<<gMM,  b, 0, stream>>>(bufB, b1, 1, W2, flags, dinv, 0, bufA, N);
    k_selfloop <<<gN32, b, 0, stream>>>(bufA, dinv, bufB, N);
    k_scatter  <<<gE32, b, 0, stream>>>(eidx, E, nrm, flags, bufA, bufB);
    k_mmh      <<<gMM,  b, 0, stream>>>(bufB, b2, 1, W3, flags, dinv, 0, bufA, N);
    k_selfloop <<<gN32, b, 0, stream>>>(bufA, dinv, bufB, N);
    k_scatter  <<<gE32, b, 0, stream>>>(eidx, E, nrm, flags, bufA, bufB);
    k_pool<<<64, b, 0, stream>>>(bufB, b3, batch, flags, gpool, N);
    k_mlp <<<1,  b, 0, stream>>>(gpool, L1w, L1b, L2w, L2b, L3w, L3b, L4w, L4b, flags, d_out);
  }
}

// Round 11
// 604.181 us; speedup vs baseline: 4.3020x; 1.0625x over previous
//
#include <hip/hip_runtime.h>
#include <hip/hip_bf16.h>

typedef __hip_bfloat16 bf16;
typedef __attribute__((ext_vector_type(8))) short bf16x8;
typedef __attribute__((ext_vector_type(4))) float f32x4;

// ---------- dtype-adaptive loads (flags are wave-uniform) ----------
__device__ __forceinline__ float ldf(const void* p, long long i, int f32){
  return f32 ? ((const float*)p)[i] : __bfloat162float(((const bf16*)p)[i]);
}
__device__ __forceinline__ int ldi(const void* p, long long i, int i64){
  return i64 ? (int)((const long long*)p)[i] : ((const int*)p)[i];
}

// ---------- sniff input dtypes once per launch ----------
__global__ void k_sniff(const void* __restrict__ x, const void* __restrict__ eidx,
                        int* __restrict__ flags){
  __shared__ int s_f, s_i;
  if (threadIdx.x == 0){ s_f = 0; s_i = 0; }
  __syncthreads();
  int t = threadIdx.x;
  const unsigned short* u = (const unsigned short*)x;
  int hits = 0;
  for (int k = t; k < 2048; k += 256){
    unsigned short v = u[2*k];
    int e = (v >> 7) & 0xFF;
    if (e == 0xFF || e == 0x00) hits++;
  }
  if (hits) atomicAdd(&s_f, 1);
  const int* ii = (const int*)eidx;
  int nz = 0;
  for (int k = t; k < 1024; k += 256){ if (ii[2*k+1] != 0) nz++; }
  if (nz) atomicAdd(&s_i, 1);
  __syncthreads();
  if (threadIdx.x == 0){
    flags[0] = s_f ? 1 : 0;   // 1 = float32, 0 = bf16
    flags[1] = s_i ? 0 : 1;   // 1 = int64,   0 = int32
  }
}

__global__ void k_zero(int* __restrict__ p, int n){
  int i = blockIdx.x*256 + threadIdx.x;
  if (i < n) p[i] = 0;
}

// ================= binned CSR build (shift=8: 256-node buckets) =================

__global__ void __launch_bounds__(256) k_bhist(const void* __restrict__ eidx, long long E,
                       const int* __restrict__ flags, int shift, int NB,
                       int* __restrict__ bcnt){
  __shared__ int h[1024];
  int t = threadIdx.x;
  for (int b = t; b < NB; b += 256) h[b] = 0;
  __syncthreads();
  int i64 = flags[1];
  long long e0 = (long long)blockIdx.x*4096;
  long long e1 = e0 + 4096; if (e1 > E) e1 = E;
  for (long long e = e0 + t; e < e1; e += 256){
    int d = ldi(eidx, E + e, i64);
    atomicAdd(&h[d >> shift], 1);
  }
  __syncthreads();
  for (int b = t; b < NB; b += 256) if (h[b]) atomicAdd(&bcnt[b], h[b]);
}

__global__ void __launch_bounds__(256) k_bscan(const int* __restrict__ bcnt, int* __restrict__ bbase,
                       int NB, int E){
  __shared__ int tmp[256];
  int t = threadIdx.x;
  int v0 = (4*t+0 < NB) ? bcnt[4*t+0] : 0;
  int v1 = (4*t+1 < NB) ? bcnt[4*t+1] : 0;
  int v2 = (4*t+2 < NB) ? bcnt[4*t+2] : 0;
  int v3 = (4*t+3 < NB) ? bcnt[4*t+3] : 0;
  int s = v0+v1+v2+v3;
  tmp[t] = s;
  __syncthreads();
  for (int st = 1; st < 256; st <<= 1){
    int add = (t >= st) ? tmp[t-st] : 0;
    __syncthreads();
    tmp[t] += add;
    __syncthreads();
  }
  int run = tmp[t] - s;
  if (4*t+0 < NB){ bbase[4*t+0] = run; run += v0; }
  if (4*t+1 < NB){ bbase[4*t+1] = run; run += v1; }
  if (4*t+2 < NB){ bbase[4*t+2] = run; run += v2; }
  if (4*t+3 < NB){ bbase[4*t+3] = run; run += v3; }
  if (t == 255) bbase[NB] = E;
}

// 4096-edge chunks, 512 threads (8 waves, 3 blocks/CU -> 24 waves/CU)
#define BINCH 4096
__global__ void __launch_bounds__(512) k_bin(const void* __restrict__ eidx, long long E,
                     const void* __restrict__ ew, const int* __restrict__ flags,
                     int shift, int NB, const int* __restrict__ bbase,
                     int* __restrict__ gcur, int2* __restrict__ csrTmp){
  __shared__ int bst[512];
  __shared__ int bcur[512];
  __shared__ int gof[512];
  __shared__ int tmp[512];
  __shared__ int2 ent[BINCH];
  __shared__ unsigned short entb[BINCH];
  int t = threadIdx.x;
  int i64 = flags[1], f32 = flags[0];
  long long e0 = (long long)blockIdx.x*BINCH;
  int cnt = (int)(((E - e0) < BINCH) ? (E - e0) : BINCH);
  int msk = (1 << shift) - 1;
  for (int b = t; b < NB; b += 512) bst[b] = 0;
  __syncthreads();
  for (int i = t; i < cnt; i += 512){
    int d = ldi(eidx, E + e0 + i, i64);
    atomicAdd(&bst[d >> shift], 1);
  }
  __syncthreads();
  int v = (t < NB) ? bst[t] : 0;
  tmp[t] = v;
  __syncthreads();
  for (int st = 1; st < 512; st <<= 1){
    int add = (t >= st) ? tmp[t-st] : 0;
    __syncthreads();
    tmp[t] += add;
    __syncthreads();
  }
  int run = tmp[t] - v;
  __syncthreads();
  if (t < NB){
    bst[t] = run; bcur[t] = run;
    if (v) gof[t] = atomicAdd(&gcur[t], v);
  }
  __syncthreads();
  for (int i = t; i < cnt; i += 512){
    int d  = ldi(eidx, E + e0 + i, i64);
    int sc = ldi(eidx, e0 + i, i64);
    float w = ldf(ew, e0 + i, f32);
    int b = d >> shift;
    int dl = d & msk;
    int pos = atomicAdd(&bcur[b], 1);
    ent[pos]  = make_int2((dl << 24) | sc, __float_as_int(w));
    entb[pos] = (unsigned short)b;
  }
  __syncthreads();
  for (int i = t; i < cnt; i += 512){
    int b = entb[i];
    int gpos = bbase[b] + gof[b] + (i - bst[b]);
    csrTmp[gpos] = ent[i];
  }
}

// per-bucket (1024 threads): counting sort by dst-low; deg/dinv/rowptr in-pass; csr.y = w*dinv[dst]
__global__ void __launch_bounds__(1024) k_bucket(const int2* __restrict__ csrTmp, const int* __restrict__ bbase,
                        int shift, int N, int E, int2* __restrict__ csr,
                        int* __restrict__ rowptr, float* __restrict__ dinv){
  __shared__ int   h[256];
  __shared__ int   st[256];
  __shared__ int   cur[256];
  __shared__ float wsum[256];
  __shared__ float sdv[256];
  int b = blockIdx.x, t = threadIdx.x;
  int base = bbase[b], cnt = bbase[b+1] - base;
  if (t < 256){ h[t] = 0; wsum[t] = 0.f; }
  __syncthreads();
  for (int i = t; i < cnt; i += 1024){
    int2 p = csrTmp[base + i];
    int dl = ((unsigned)p.x) >> 24;
    atomicAdd(&h[dl], 1);
    atomicAdd(&wsum[dl], __int_as_float(p.y));
  }
  __syncthreads();
  int c = (t < 256) ? h[t] : 0;
  if (t < 256) st[t] = c;
  __syncthreads();
  for (int s2 = 1; s2 < 256; s2 <<= 1){
    int add = (t >= s2 && t < 256) ? st[t-s2] : 0;
    __syncthreads();
    if (t < 256) st[t] += add;
    __syncthreads();
  }
  if (t < 256){
    int ex = st[t] - c;
    cur[t] = ex;
    int n = (b << shift) + t;
    if (n < N){
      float deg = 1.f + wsum[t];
      float di = (deg > 0.f) ? rsqrtf(fmaxf(deg, 1e-30f)) : 0.f;
      sdv[t] = di;
      dinv[n] = di;
      rowptr[n] = base + ex;
      if (n == N-1) rowptr[N] = E;
    }
  }
  __syncthreads();
  for (int i = t; i < cnt; i += 1024){
    int2 p = csrTmp[base + i];
    int dl = ((unsigned)p.x) >> 24;
    int pos = atomicAdd(&cur[dl], 1);
    float nm = __int_as_float(p.y) * sdv[dl];       // w * dinv[dst]
    csr[base + pos] = make_int2(p.x & 0xFFFFFF, __float_as_int(nm));
  }
}

// ---------- pull: wave/node, 2-way unrolled ----------
// zp = dinv*(hW); agg[n] = dinv[n]*zp[n] + sum csr.y*zp[src]
__global__ void k_pull(const int2* __restrict__ csr, const int* __restrict__ rowptr,
                       const float* __restrict__ dinv, const float* __restrict__ zp,
                       float* __restrict__ agg, int N){
  int n = blockIdx.x*4 + (threadIdx.x >> 6);
  int lane = threadIdx.x & 63;
  if (n >= N) return;
  int g = lane >> 3;            // edge subgroup 0..7
  int q = lane & 7;             // feature quad 0..7
  const float4* h4 = (const float4*)zp;
  int s0 = rowptr[n], s1 = rowptr[n+1];
  float4 acc = make_float4(0.f,0.f,0.f,0.f);
  if (g == 0){
    float di = dinv[n];
    float4 hv = h4[(long long)n*8 + q];
    acc.x = di*hv.x; acc.y = di*hv.y; acc.z = di*hv.z; acc.w = di*hv.w;
  }
  int j = s0 + g;
  for (; j + 8 < s1; j += 16){
    int2 p0 = csr[j];
    int2 p1 = csr[j+8];
    float nm0 = __int_as_float(p0.y);
    float nm1 = __int_as_float(p1.y);
    float4 h0 = h4[(long long)p0.x*8 + q];
    float4 h1 = h4[(long long)p1.x*8 + q];
    acc.x = fmaf(nm0, h0.x, acc.x); acc.y = fmaf(nm0, h0.y, acc.y);
    acc.z = fmaf(nm0, h0.z, acc.z); acc.w = fmaf(nm0, h0.w, acc.w);
    acc.x = fmaf(nm1, h1.x, acc.x); acc.y = fmaf(nm1, h1.y, acc.y);
    acc.z = fmaf(nm1, h1.z, acc.z); acc.w = fmaf(nm1, h1.w, acc.w);
  }
  if (j < s1){
    int2 p = csr[j];
    float nm = __int_as_float(p.y);
    float4 hv = h4[(long long)p.x*8 + q];
    acc.x = fmaf(nm, hv.x, acc.x); acc.y = fmaf(nm, hv.y, acc.y);
    acc.z = fmaf(nm, hv.z, acc.z); acc.w = fmaf(nm, hv.w, acc.w);
  }
  #pragma unroll
  for (int st = 8; st < 64; st <<= 1){
    acc.x += __shfl_xor(acc.x, st, 64);
    acc.y += __shfl_xor(acc.y, st, 64);
    acc.z += __shfl_xor(acc.z, st, 64);
    acc.w += __shfl_xor(acc.w, st, 64);
  }
  if (g == 0) ((float4*)agg)[(long long)n*8 + q] = acc;
}

// ---------- layer-1 matmul ----------
// bf16 mode: MFMA 16x16x32. One wave per 16-row tile, 4 waves/block (64 rows).
// A frag: A[m=lane&15][k=quad*8+j] straight from global bf16 (16B/lane loads).
// B frag: B[k=quad*8+j][n=lane&15] from W (L2-hot). D: col=lane&15,row=quad*4+r.
// f32 mode: legacy LDS-staged scalar path.
__global__ void __launch_bounds__(256) k_mm1(const void* __restrict__ x, const void* __restrict__ W,
                      const int* __restrict__ flags, const float* __restrict__ dinv,
                      int mul_dinv, float* __restrict__ out, int N){
  __shared__ float Ws[128*32];
  __shared__ float xs[32*128];
  int f32 = flags[0];
  if (!f32){
    int wave = threadIdx.x >> 6;
    int lane = threadIdx.x & 63;
    int m = lane & 15, quad = lane >> 4;
    long long tile = (long long)blockIdx.x*4 + wave;
    int row0 = (int)(tile*16);
    if (row0 >= N) return;
    const short* xp = (const short*)x;
    const short* wp = (const short*)W;
    int row = row0 + m;
    bool rv = row < N;
    bf16x8 a[4];
    #pragma unroll
    for (int kc = 0; kc < 4; ++kc){
      if (rv) a[kc] = *(const bf16x8*)(xp + (long long)row*128 + kc*32 + quad*8);
      else    a[kc] = (bf16x8)(short)0;
    }
    #pragma unroll
    for (int nt = 0; nt < 2; ++nt){
      f32x4 acc = {0.f,0.f,0.f,0.f};
      #pragma unroll
      for (int kc = 0; kc < 4; ++kc){
        bf16x8 bfr;
        #pragma unroll
        for (int j = 0; j < 8; ++j)
          bfr[j] = wp[(kc*32 + quad*8 + j)*32 + nt*16 + m];
        acc = __builtin_amdgcn_mfma_f32_16x16x32_bf16(a[kc], bfr, acc, 0, 0, 0);
      }
      #pragma unroll
      for (int r = 0; r < 4; ++r){
        int rr = row0 + quad*4 + r;
        if (rr < N){
          float v = acc[r];
          out[(long long)rr*32 + nt*16 + m] = mul_dinv ? v*dinv[rr] : v;
        }
      }
    }
    return;
  }
  // ---- f32 fallback (legacy) ----
  int tid = threadIdx.x;
  for (int i = tid; i < 4096; i += 256) Ws[i] = ((const float*)W)[i];
  int n0 = blockIdx.x*32;
  for (int i = tid; i < 4096; i += 256){
    int r = i >> 7, k = i & 127, n = n0 + r;
    xs[i] = (n < N) ? ((const float*)x)[(long long)n*128 + k] : 0.f;
  }
  __syncthreads();
  int f = tid & 31, r = tid >> 5;
  float a0=0.f, a1=0.f, a2=0.f, a3=0.f;
  for (int k = 0; k < 128; ++k){
    float w = Ws[k*32+f];
    a0 = fmaf(xs[(r    )*128+k], w, a0);
    a1 = fmaf(xs[(r+ 8)*128+k], w, a1);
    a2 = fmaf(xs[(r+16)*128+k], w, a2);
    a3 = fmaf(xs[(r+24)*128+k], w, a3);
  }
  int n;
  n = n0+r;    if (n < N) out[n*32+f] = mul_dinv ? a0*dinv[n] : a0;
  n = n0+r+8;  if (n < N) out[n*32+f] = mul_dinv ? a1*dinv[n] : a1;
  n = n0+r+16; if (n < N) out[n*32+f] = mul_dinv ? a2*dinv[n] : a2;
  n = n0+r+24; if (n < N) out[n*32+f] = mul_dinv ? a3*dinv[n] : a3;
}

// ---------- hidden matmul: W transposed in LDS (stride 36), float4 LDS reads ----------
__global__ void k_mmh(const float* __restrict__ in, const void* __restrict__ bias, int do_relu,
                      const void* __restrict__ W, const int* __restrict__ flags,
                      const float* __restrict__ dinv, int mul_dinv,
                      float* __restrict__ out, int N){
  __shared__ float Wt[32*36];      // Wt[f][k], stride 36 (16B-aligned rows, 4-way max alias)
  __shared__ float xs[32*32];
  int tid = threadIdx.x;
  int f32 = flags[0];
  for (int i = tid; i < 1024; i += 256){
    int k = i >> 5, f = i & 31;
    Wt[f*36 + k] = ldf(W, i, f32);
  }
  int n0 = blockIdx.x*32;
  for (int i = tid; i < 1024; i += 256){
    int r = i >> 5, k = i & 31, n = n0 + r;
    float v = 0.f;
    if (n < N){
      v = in[(long long)n*32+k] + ldf(bias, k, f32);
      if (do_relu) v = fmaxf(v, 0.f);
    }
    xs[i] = v;
  }
  __syncthreads();
  int f = tid & 31, r = tid >> 5;
  const float4* xs4 = (const float4*)xs;
  float a0=0.f, a1=0.f, a2=0.f, a3=0.f;
  #pragma unroll
  for (int kc = 0; kc < 8; ++kc){
    float4 wv = *(const float4*)&Wt[f*36 + kc*4];
    float4 x0 = xs4[(r    )*8 + kc];
    float4 x1 = xs4[(r+ 8)*8 + kc];
    float4 x2 = xs4[(r+16)*8 + kc];
    float4 x3 = xs4[(r+24)*8 + kc];
    a0 = fmaf(x0.x,wv.x,fmaf(x0.y,wv.y,fmaf(x0.z,wv.z,fmaf(x0.w,wv.w,a0))));
    a1 = fmaf(x1.x,wv.x,fmaf(x1.y,wv.y,fmaf(x1.z,wv.z,fmaf(x1.w,wv.w,a1))));
    a2 = fmaf(x2.x,wv.x,fmaf(x2.y,wv.y,fmaf(x2.z,wv.z,fmaf(x2.w,wv.w,a2))));
    a3 = fmaf(x3.x,wv.x,fmaf(x3.y,wv.y,fmaf(x3.z,wv.z,fmaf(x3.w,wv.w,a3))));
  }
  int n;
  n = n0+r;    if (n < N) out[n*32+f] = mul_dinv ? a0*dinv[n] : a0;
  n = n0+r+8;  if (n < N) out[n*32+f] = mul_dinv ? a1*dinv[n] : a1;
  n = n0+r+16; if (n < N) out[n*32+f] = mul_dinv ? a2*dinv[n] : a2;
  n = n0+r+24; if (n < N) out[n*32+f] = mul_dinv ? a3*dinv[n] : a3;
}

// ---------- mean pool per graph (batch sorted) ----------
__device__ __forceinline__ int lower_bound_i(const void* __restrict__ a, int n, int v, int i64){
  int lo = 0, hi = n;
  while (lo < hi){ int mid = (lo+hi) >> 1; if (ldi(a, mid, i64) < v) lo = mid+1; else hi = mid; }
  return lo;
}

__global__ void k_pool(const float* __restrict__ agg, const void* __restrict__ b3,
                       const void* __restrict__ batch, const int* __restrict__ flags,
                       float* __restrict__ gpool, int N){
  int f32 = flags[0], i64 = flags[1];
  int g = blockIdx.x;
  int start = lower_bound_i(batch, N, g, i64);
  int end   = lower_bound_i(batch, N, g+1, i64);
  int tid = threadIdx.x;
  int f = tid & 31, r = tid >> 5;
  float acc = 0.f;
  for (int n = start + r; n < end; n += 8) acc += agg[n*32+f];
  __shared__ float red[8][32];
  red[r][f] = acc;
  __syncthreads();
  if (r == 0){
    float s = red[0][f];
    #pragma unroll
    for (int j = 1; j < 8; ++j) s += red[j][f];
    int c = end - start;
    float gv = (c > 0) ? (s / (float)c + ldf(b3, f, f32)) : 0.f;
    gpool[g*32+f] = gv;
  }
}

// ---------- MLP head: 1 block, column-per-thread, 16 row-accumulators (ILP) ----------
__global__ void __launch_bounds__(256, 1) k_mlp(const float* __restrict__ gpool,
                      const void* __restrict__ L1w, const void* __restrict__ L1b,
                      const void* __restrict__ L2w, const void* __restrict__ L2b,
                      const void* __restrict__ L3w, const void* __restrict__ L3b,
                      const void* __restrict__ L4w, const void* __restrict__ L4b,
                      const int* __restrict__ flags, void* __restrict__ out){
  __shared__ float gin[64*32];
  __shared__ float A[64*65];
  __shared__ float B[64*65];
  __shared__ float ws[64*64];
  __shared__ float wb[64];
  int tid = threadIdx.x;
  int f32 = flags[0];
  int j  = tid & 63;
  int i0 = tid >> 6;
  float acc[16];

  for (int i = tid; i < 64*32; i += 256) gin[i] = gpool[i];
  for (int i = tid; i < 2048; i += 256) ws[i] = ldf(L1w, i, f32);
  if (tid < 64) wb[tid] = ldf(L1b, tid, f32);
  __syncthreads();
  #pragma unroll
  for (int r = 0; r < 16; ++r) acc[r] = wb[j];
  for (int k = 0; k < 32; ++k){
    float w = ws[k*64+j];
    #pragma unroll
    for (int r = 0; r < 16; ++r) acc[r] = fmaf(gin[(i0+4*r)*32+k], w, acc[r]);
  }
  #pragma unroll
  for (int r = 0; r < 16; ++r) A[(i0+4*r)*65+j] = fmaxf(acc[r], 0.f);
  __syncthreads();
  for (int i = tid; i < 4096; i += 256) ws[i] = ldf(L2w, i, f32);
  if (tid < 64) wb[tid] = ldf(L2b, tid, f32);
  __syncthreads();
  #pragma unroll
  for (int r = 0; r < 16; ++r) acc[r] = wb[j];
  for (int k = 0; k < 64; ++k){
    float w = ws[k*64+j];
    #pragma unroll
    for (int r = 0; r < 16; ++r) acc[r] = fmaf(A[(i0+4*r)*65+k], w, acc[r]);
  }
  #pragma unroll
  for (int r = 0; r < 16; ++r) B[(i0+4*r)*65+j] = fmaxf(acc[r], 0.f);
  __syncthreads();
  for (int i = tid; i < 4096; i += 256) ws[i] = ldf(L3w, i, f32);
  if (tid < 64) wb[tid] = ldf(L3b, tid, f32);
  __syncthreads();
  #pragma unroll
  for (int r = 0; r < 16; ++r) acc[r] = wb[j];
  for (int k = 0; k < 64; ++k){
    float w = ws[k*64+j];
    #pragma unroll
    for (int r = 0; r < 16; ++r) acc[r] = fmaf(B[(i0+4*r)*65+k], w, acc[r]);
  }
  #pragma unroll
  for (int r = 0; r < 16; ++r) A[(i0+4*r)*65+j] = fmaxf(acc[r], 0.f);
  __syncthreads();
  for (int i = tid; i < 640; i += 256) ws[i] = ldf(L4w, i, f32);
  if (tid < 10) wb[tid] = ldf(L4b, tid, f32);
  __syncthreads();
  if (tid < 64){
    int row = tid;
    float a10[10];
    #pragma unroll
    for (int c = 0; c < 10; ++c) a10[c] = wb[c];
    for (int k = 0; k < 64; ++k){
      float av = A[row*65+k];
      #pragma unroll
      for (int c = 0; c < 10; ++c) a10[c] = fmaf(av, ws[k*10+c], a10[c]);
    }
    #pragma unroll
    for (int c = 0; c < 10; ++c){
      if (f32) ((float*)out)[row*10+c] = a10[c];
      else     ((bf16*)out)[row*10+c]  = __float2bfloat16(a10[c]);
    }
  }
}

// ---------- fallback (atomic-scatter path, small ws) ----------
__global__ void k_init_deg(float* __restrict__ deg, int N){
  int i = blockIdx.x*256 + threadIdx.x;
  if (i < N) deg[i] = 1.0f;
}
__global__ void k_deg_accum(const void* __restrict__ eidx, long long E,
                            const void* __restrict__ w, const int* __restrict__ flags,
                            float* __restrict__ deg){
  long long e = (long long)blockIdx.x*256 + threadIdx.x;
  if (e < E){
    int f32 = flags[0], i64 = flags[1];
    atomicAdd(&deg[ldi(eidx, E + e, i64)], ldf(w, e, f32));
  }
}
__global__ void k_dinv(float* __restrict__ deg, int N){
  int i = blockIdx.x*256 + threadIdx.x;
  if (i < N){
    float d = deg[i];
    deg[i] = (d > 0.f) ? rsqrtf(fmaxf(d, 1e-30f)) : 0.f;
  }
}
__global__ void k_norm(const void* __restrict__ eidx, long long E,
                       const void* __restrict__ w, const float* __restrict__ dinv,
                       const int* __restrict__ flags, float* __restrict__ nrm){
  long long e = (long long)blockIdx.x*256 + threadIdx.x;
  if (e < E){
    int f32 = flags[0], i64 = flags[1];
    int s = ldi(eidx, e, i64), d = ldi(eidx, E + e, i64);
    nrm[e] = dinv[s] * ldf(w, e, f32) * dinv[d];
  }
}
__global__ void k_selfloop(const float* __restrict__ hlin, const float* __restrict__ dinv,
                           float* __restrict__ agg, int N){
  int idx = blockIdx.x*256 + threadIdx.x;
  if (idx < N*32){
    int n = idx >> 5;
    float di = dinv[n];
    agg[idx] = di*di*hlin[idx];
  }
}
__global__ void k_scatter(const void* __restrict__ eidx, long long E,
                          const float* __restrict__ nrm, const int* __restrict__ flags,
                          const float* __restrict__ hlin, float* __restrict__ agg){
  long long idx = (long long)blockIdx.x*256 + threadIdx.x;
  if (idx < E*32){
    int i64 = flags[1];
    long long e = idx >> 5;
    int f = (int)(idx & 31);
    int s = ldi(eidx, e, i64), d = ldi(eidx, E + e, i64);
    atomicAdd(&agg[(long long)d*32 + f], nrm[e] * hlin[(long long)s*32 + f]);
  }
}

extern "C" void kernel_launch(void* const* d_in, const int* in_sizes, int n_in,
                              void* d_out, int out_size, void* d_ws, size_t ws_size,
                              hipStream_t stream){
  const void* x   = d_in[0];
  const void* ew  = d_in[1];
  const void* W1  = d_in[2];
  const void* b1  = d_in[3];
  const void* W2  = d_in[4];
  const void* b2  = d_in[5];
  const void* W3  = d_in[6];
  const void* b3  = d_in[7];
  const void* L1w = d_in[8];  const void* L1b = d_in[9];
  const void* L2w = d_in[10]; const void* L2b = d_in[11];
  const void* L3w = d_in[12]; const void* L3b = d_in[13];
  const void* L4w = d_in[14]; const void* L4b = d_in[15];
  const void* eidx  = d_in[16];
  const void* batch = d_in[17];
  const long long E = in_sizes[1];
  const int N = in_sizes[17];

  dim3 b(256);
  int gN   = (N + 255)/256;
  int gE   = (int)((E + 255)/256);
  int gMM  = (N + 31)/32;
  int gMM1 = (N + 63)/64;     // MFMA k_mm1: 64 rows/block (4 waves x 16)
  int gNd4 = (N + 3)/4;
  int gBH  = (int)((E + 4095)/4096);
  int gBN  = (int)((E + BINCH - 1)/BINCH);

  const int shift = 8;                       // 256-node buckets
  int NB = (N + 255) >> 8;

  auto AL = [](size_t v){ return (v + 255) & ~(size_t)255; };

  char* base = (char*)d_ws;
  size_t off = 0;
  size_t o_flags = off; off += AL(64*4);
  size_t o_rowp  = off; off += AL((size_t)(N+1)*4);
  size_t o_dinv  = off; off += AL((size_t)N*4);
  size_t o_bbase = off; off += AL((size_t)(NB+1)*4);
  size_t o_bcnt  = off; off += AL((size_t)NB*4) + AL((size_t)NB*4);   // bcnt + gcur
  size_t o_csr   = off; off += AL((size_t)E*8);
  size_t o_tmp   = off; off += AL((size_t)E*8);
  size_t o_bufA  = off; off += AL((size_t)N*128);
  size_t o_bufB  = off; off += AL((size_t)N*128);
  size_t o_gp    = off; off += AL(2048*4);
  size_t needed  = off;

  if (ws_size >= needed && NB <= 512 && N < (1<<24)){
    int*   flags  = (int*)(base + o_flags);
    int*   rowptr = (int*)(base + o_rowp);
    float* dinv   = (float*)(base + o_dinv);
    int*   bbase  = (int*)(base + o_bbase);
    int*   bcnt   = (int*)(base + o_bcnt);
    int*   gcur   = (int*)(base + o_bcnt + AL((size_t)NB*4));
    int2*  csr    = (int2*)(base + o_csr);
    int2*  csrTmp = (int2*)(base + o_tmp);
    float* bufA   = (float*)(base + o_bufA);
    float* bufB   = (float*)(base + o_bufB);
    float* gpool  = (float*)(base + o_gp);

    k_sniff <<<1,    b, 0, stream>>>(x, eidx, flags);
    k_zero  <<<(int)((AL((size_t)NB*4)/4 + NB + 255)/256), b, 0, stream>>>(bcnt, (int)(AL((size_t)NB*4)/4 + NB));
    k_bhist <<<gBH,  b, 0, stream>>>(eidx, E, flags, shift, NB, bcnt);
    k_bscan <<<1,    b, 0, stream>>>(bcnt, bbase, NB, (int)E);
    k_bin   <<<gBN,  dim3(512), 0, stream>>>(eidx, E, ew, flags, shift, NB, bbase, gcur, csrTmp);
    k_bucket<<<NB,   dim3(1024), 0, stream>>>(csrTmp, bbase, shift, N, (int)E, csr, rowptr, dinv);
    // layer 1
    k_mm1   <<<gMM1, b, 0, stream>>>(x, W1, flags, dinv, 1, bufA, N);
    k_pull  <<<gNd4, b, 0, stream>>>(csr, rowptr, dinv, bufA, bufB, N);
    // layer 2
    k_mmh   <<<gMM,  b, 0, stream>>>(bufB, b1, 1, W2, flags, dinv, 1, bufA, N);
    k_pull  <<<gNd4, b, 0, stream>>>(csr, rowptr, dinv, bufA, bufB, N);
    // layer 3
    k_mmh   <<<gMM,  b, 0, stream>>>(bufB, b2, 1, W3, flags, dinv, 1, bufA, N);
    k_pull  <<<gNd4, b, 0, stream>>>(csr, rowptr, dinv, bufA, bufB, N);
    // head
    k_pool<<<64, b, 0, stream>>>(bufB, b3, batch, flags, gpool, N);
    k_mlp <<<1,  b, 0, stream>>>(gpool, L1w, L1b, L2w, L2b, L3w, L3b, L4w, L4b, flags, d_out);
    return;
  }

  // ---- fallback: atomic-scatter path ----
  {
    float* wf    = (float*)d_ws;
    int*   flags = (int*)d_ws;
    size_t Npad  = ((size_t)N + 255) & ~(size_t)255;
    float* dinv  = wf + 64;
    float* nrm   = dinv + Npad;
    float* bufA  = nrm + E;
    float* bufB  = bufA + (size_t)N*32;
    float* gpool = bufB + (size_t)N*32;
    int gN32 = (N*32 + 255)/256;
    int gE32 = (int)((E*32 + 255)/256);

    k_sniff    <<<1,    b, 0, stream>>>(x, eidx, flags);
    k_init_deg <<<gN,   b, 0, stream>>>(dinv, N);
    k_deg_accum<<<gE,   b, 0, stream>>>(eidx, E, ew, flags, dinv);
    k_dinv     <<<gN,   b, 0, stream>>>(dinv, N);
    k_norm     <<<gE,   b, 0, stream>>>(eidx, E, ew, dinv, flags, nrm);
    k_mm1      <<<gMM1, b, 0, stream>>>(x, W1, flags, dinv, 0, bufA, N);
    k_selfloop <<<gN32, b, 0, stream>>>(bufA, dinv, bufB, N);
    k_scatter  <<<gE32, b, 0, stream>>>(eidx, E, nrm, flags, bufA, bufB);
    k_mmh      <<<gMM,  b, 0, stream>>>(bufB, b1, 1, W2, flags, dinv, 0, bufA, N);
    k_selfloop <<<gN32, b, 0, stream>>>(bufA, dinv, bufB, N);
    k_scatter  <<<gE32, b, 0, stream>>>(eidx, E, nrm, flags, bufA, bufB);
    k_mmh      <<<gMM,  b, 0, stream>>>(bufB, b2, 1, W3, flags, dinv, 0, bufA, N);
    k_selfloop <<<gN32, b, 0, stream>>>(bufA, dinv, bufB, N);
    k_scatter  <<<gE32, b, 0, stream>>>(eidx, E, nrm, flags, bufA, bufB);
    k_pool<<<64, b, 0, stream>>>(bufB, b3, batch, flags, gpool, N);
    k_mlp <<<1,  b, 0, stream>>>(gpool, L1w, L1b, L2w, L2b, L3w, L3b, L4w, L4b, flags, d_out);
  }
}

// Round 12
// 566.328 us; speedup vs baseline: 4.5896x; 1.0668x over previous
//
#include <hip/hip_runtime.h>
#include <hip/hip_bf16.h>

typedef __hip_bfloat16 bf16;
typedef __attribute__((ext_vector_type(8))) short bf16x8;
typedef __attribute__((ext_vector_type(4))) float f32x4;

// ---------- dtype-adaptive loads (flags are wave-uniform) ----------
__device__ __forceinline__ float ldf(const void* p, long long i, int f32){
  return f32 ? ((const float*)p)[i] : __bfloat162float(((const bf16*)p)[i]);
}
__device__ __forceinline__ int ldi(const void* p, long long i, int i64){
  return i64 ? (int)((const long long*)p)[i] : ((const int*)p)[i];
}

// ---------- sniff input dtypes once per launch ----------
__global__ void k_sniff(const void* __restrict__ x, const void* __restrict__ eidx,
                        int* __restrict__ flags){
  __shared__ int s_f, s_i;
  if (threadIdx.x == 0){ s_f = 0; s_i = 0; }
  __syncthreads();
  int t = threadIdx.x;
  const unsigned short* u = (const unsigned short*)x;
  int hits = 0;
  for (int k = t; k < 2048; k += 256){
    unsigned short v = u[2*k];
    int e = (v >> 7) & 0xFF;
    if (e == 0xFF || e == 0x00) hits++;
  }
  if (hits) atomicAdd(&s_f, 1);
  const int* ii = (const int*)eidx;
  int nz = 0;
  for (int k = t; k < 1024; k += 256){ if (ii[2*k+1] != 0) nz++; }
  if (nz) atomicAdd(&s_i, 1);
  __syncthreads();
  if (threadIdx.x == 0){
    flags[0] = s_f ? 1 : 0;   // 1 = float32, 0 = bf16
    flags[1] = s_i ? 0 : 1;   // 1 = int64,   0 = int32
  }
}

__global__ void k_zero(int* __restrict__ p, int n){
  int i = blockIdx.x*256 + threadIdx.x;
  if (i < n) p[i] = 0;
}

// ================= binned CSR build (shift=8: 256-node buckets) =================

__global__ void __launch_bounds__(256) k_bhist(const void* __restrict__ eidx, long long E,
                       const int* __restrict__ flags, int shift, int NB,
                       int* __restrict__ bcnt){
  __shared__ int h[1024];
  int t = threadIdx.x;
  for (int b = t; b < NB; b += 256) h[b] = 0;
  __syncthreads();
  int i64 = flags[1];
  long long e0 = (long long)blockIdx.x*4096;
  long long e1 = e0 + 4096; if (e1 > E) e1 = E;
  for (long long e = e0 + t; e < e1; e += 256){
    int d = ldi(eidx, E + e, i64);
    atomicAdd(&h[d >> shift], 1);
  }
  __syncthreads();
  for (int b = t; b < NB; b += 256) if (h[b]) atomicAdd(&bcnt[b], h[b]);
}

__global__ void __launch_bounds__(256) k_bscan(const int* __restrict__ bcnt, int* __restrict__ bbase,
                       int NB, int E){
  __shared__ int tmp[256];
  int t = threadIdx.x;
  int v0 = (4*t+0 < NB) ? bcnt[4*t+0] : 0;
  int v1 = (4*t+1 < NB) ? bcnt[4*t+1] : 0;
  int v2 = (4*t+2 < NB) ? bcnt[4*t+2] : 0;
  int v3 = (4*t+3 < NB) ? bcnt[4*t+3] : 0;
  int s = v0+v1+v2+v3;
  tmp[t] = s;
  __syncthreads();
  for (int st = 1; st < 256; st <<= 1){
    int add = (t >= st) ? tmp[t-st] : 0;
    __syncthreads();
    tmp[t] += add;
    __syncthreads();
  }
  int run = tmp[t] - s;
  if (4*t+0 < NB){ bbase[4*t+0] = run; run += v0; }
  if (4*t+1 < NB){ bbase[4*t+1] = run; run += v1; }
  if (4*t+2 < NB){ bbase[4*t+2] = run; run += v2; }
  if (4*t+3 < NB){ bbase[4*t+3] = run; run += v3; }
  if (t == 255) bbase[NB] = E;
}

// 4096-edge chunks, 512 threads (8 waves, 3 blocks/CU -> 24 waves/CU)
#define BINCH 4096
__global__ void __launch_bounds__(512) k_bin(const void* __restrict__ eidx, long long E,
                     const void* __restrict__ ew, const int* __restrict__ flags,
                     int shift, int NB, const int* __restrict__ bbase,
                     int* __restrict__ gcur, int2* __restrict__ csrTmp){
  __shared__ int bst[512];
  __shared__ int bcur[512];
  __shared__ int gof[512];
  __shared__ int tmp[512];
  __shared__ int2 ent[BINCH];
  __shared__ unsigned short entb[BINCH];
  int t = threadIdx.x;
  int i64 = flags[1], f32 = flags[0];
  long long e0 = (long long)blockIdx.x*BINCH;
  int cnt = (int)(((E - e0) < BINCH) ? (E - e0) : BINCH);
  int msk = (1 << shift) - 1;
  for (int b = t; b < NB; b += 512) bst[b] = 0;
  __syncthreads();
  for (int i = t; i < cnt; i += 512){
    int d = ldi(eidx, E + e0 + i, i64);
    atomicAdd(&bst[d >> shift], 1);
  }
  __syncthreads();
  int v = (t < NB) ? bst[t] : 0;
  tmp[t] = v;
  __syncthreads();
  for (int st = 1; st < 512; st <<= 1){
    int add = (t >= st) ? tmp[t-st] : 0;
    __syncthreads();
    tmp[t] += add;
    __syncthreads();
  }
  int run = tmp[t] - v;
  __syncthreads();
  if (t < NB){
    bst[t] = run; bcur[t] = run;
    if (v) gof[t] = atomicAdd(&gcur[t], v);
  }
  __syncthreads();
  for (int i = t; i < cnt; i += 512){
    int d  = ldi(eidx, E + e0 + i, i64);
    int sc = ldi(eidx, e0 + i, i64);
    float w = ldf(ew, e0 + i, f32);
    int b = d >> shift;
    int dl = d & msk;
    int pos = atomicAdd(&bcur[b], 1);
    ent[pos]  = make_int2((dl << 24) | sc, __float_as_int(w));
    entb[pos] = (unsigned short)b;
  }
  __syncthreads();
  for (int i = t; i < cnt; i += 512){
    int b = entb[i];
    int gpos = bbase[b] + gof[b] + (i - bst[b]);
    csrTmp[gpos] = ent[i];
  }
}

// per-bucket (1024 threads): counting sort by dst-low; deg/dinv/rowptr in-pass; csr.y = w*dinv[dst]
__global__ void __launch_bounds__(1024) k_bucket(const int2* __restrict__ csrTmp, const int* __restrict__ bbase,
                        int shift, int N, int E, int2* __restrict__ csr,
                        int* __restrict__ rowptr, float* __restrict__ dinv){
  __shared__ int   h[256];
  __shared__ int   st[256];
  __shared__ int   cur[256];
  __shared__ float wsum[256];
  __shared__ float sdv[256];
  int b = blockIdx.x, t = threadIdx.x;
  int base = bbase[b], cnt = bbase[b+1] - base;
  if (t < 256){ h[t] = 0; wsum[t] = 0.f; }
  __syncthreads();
  for (int i = t; i < cnt; i += 1024){
    int2 p = csrTmp[base + i];
    int dl = ((unsigned)p.x) >> 24;
    atomicAdd(&h[dl], 1);
    atomicAdd(&wsum[dl], __int_as_float(p.y));
  }
  __syncthreads();
  int c = (t < 256) ? h[t] : 0;
  if (t < 256) st[t] = c;
  __syncthreads();
  for (int s2 = 1; s2 < 256; s2 <<= 1){
    int add = (t >= s2 && t < 256) ? st[t-s2] : 0;
    __syncthreads();
    if (t < 256) st[t] += add;
    __syncthreads();
  }
  if (t < 256){
    int ex = st[t] - c;
    cur[t] = ex;
    int n = (b << shift) + t;
    if (n < N){
      float deg = 1.f + wsum[t];
      float di = (deg > 0.f) ? rsqrtf(fmaxf(deg, 1e-30f)) : 0.f;
      sdv[t] = di;
      dinv[n] = di;
      rowptr[n] = base + ex;
      if (n == N-1) rowptr[N] = E;
    }
  }
  __syncthreads();
  for (int i = t; i < cnt; i += 1024){
    int2 p = csrTmp[base + i];
    int dl = ((unsigned)p.x) >> 24;
    int pos = atomicAdd(&cur[dl], 1);
    float nm = __int_as_float(p.y) * sdv[dl];       // w * dinv[dst]
    csr[base + pos] = make_int2(p.x & 0xFFFFFF, __float_as_int(nm));
  }
}

// ---------- pull: wave/node, 2-way unrolled ----------
// zp = dinv*(hW); agg[n] = dinv[n]*zp[n] + sum csr.y*zp[src]
__global__ void k_pull(const int2* __restrict__ csr, const int* __restrict__ rowptr,
                       const float* __restrict__ dinv, const float* __restrict__ zp,
                       float* __restrict__ agg, int N){
  int n = blockIdx.x*4 + (threadIdx.x >> 6);
  int lane = threadIdx.x & 63;
  if (n >= N) return;
  int g = lane >> 3;            // edge subgroup 0..7
  int q = lane & 7;             // feature quad 0..7
  const float4* h4 = (const float4*)zp;
  int s0 = rowptr[n], s1 = rowptr[n+1];
  float4 acc = make_float4(0.f,0.f,0.f,0.f);
  if (g == 0){
    float di = dinv[n];
    float4 hv = h4[(long long)n*8 + q];
    acc.x = di*hv.x; acc.y = di*hv.y; acc.z = di*hv.z; acc.w = di*hv.w;
  }
  int j = s0 + g;
  for (; j + 8 < s1; j += 16){
    int2 p0 = csr[j];
    int2 p1 = csr[j+8];
    float nm0 = __int_as_float(p0.y);
    float nm1 = __int_as_float(p1.y);
    float4 h0 = h4[(long long)p0.x*8 + q];
    float4 h1 = h4[(long long)p1.x*8 + q];
    acc.x = fmaf(nm0, h0.x, acc.x); acc.y = fmaf(nm0, h0.y, acc.y);
    acc.z = fmaf(nm0, h0.z, acc.z); acc.w = fmaf(nm0, h0.w, acc.w);
    acc.x = fmaf(nm1, h1.x, acc.x); acc.y = fmaf(nm1, h1.y, acc.y);
    acc.z = fmaf(nm1, h1.z, acc.z); acc.w = fmaf(nm1, h1.w, acc.w);
  }
  if (j < s1){
    int2 p = csr[j];
    float nm = __int_as_float(p.y);
    float4 hv = h4[(long long)p.x*8 + q];
    acc.x = fmaf(nm, hv.x, acc.x); acc.y = fmaf(nm, hv.y, acc.y);
    acc.z = fmaf(nm, hv.z, acc.z); acc.w = fmaf(nm, hv.w, acc.w);
  }
  #pragma unroll
  for (int st = 8; st < 64; st <<= 1){
    acc.x += __shfl_xor(acc.x, st, 64);
    acc.y += __shfl_xor(acc.y, st, 64);
    acc.z += __shfl_xor(acc.z, st, 64);
    acc.w += __shfl_xor(acc.w, st, 64);
  }
  if (g == 0) ((float4*)agg)[(long long)n*8 + q] = acc;
}

// ---------- layer-1 matmul ----------
// bf16 mode: MFMA 16x16x32, one wave per 16-row tile; f32 mode: legacy scalar path.
__global__ void __launch_bounds__(256) k_mm1(const void* __restrict__ x, const void* __restrict__ W,
                      const int* __restrict__ flags, const float* __restrict__ dinv,
                      int mul_dinv, float* __restrict__ out, int N){
  __shared__ float Ws[128*32];
  __shared__ float xs[32*128];
  int f32 = flags[0];
  if (!f32){
    int wave = threadIdx.x >> 6;
    int lane = threadIdx.x & 63;
    int m = lane & 15, quad = lane >> 4;
    long long tile = (long long)blockIdx.x*4 + wave;
    int row0 = (int)(tile*16);
    if (row0 >= N) return;
    const short* xp = (const short*)x;
    const short* wp = (const short*)W;
    int row = row0 + m;
    bool rv = row < N;
    bf16x8 a[4];
    #pragma unroll
    for (int kc = 0; kc < 4; ++kc){
      if (rv) a[kc] = *(const bf16x8*)(xp + (long long)row*128 + kc*32 + quad*8);
      else    a[kc] = (bf16x8)(short)0;
    }
    #pragma unroll
    for (int nt = 0; nt < 2; ++nt){
      f32x4 acc = {0.f,0.f,0.f,0.f};
      #pragma unroll
      for (int kc = 0; kc < 4; ++kc){
        bf16x8 bfr;
        #pragma unroll
        for (int j = 0; j < 8; ++j)
          bfr[j] = wp[(kc*32 + quad*8 + j)*32 + nt*16 + m];
        acc = __builtin_amdgcn_mfma_f32_16x16x32_bf16(a[kc], bfr, acc, 0, 0, 0);
      }
      #pragma unroll
      for (int r = 0; r < 4; ++r){
        int rr = row0 + quad*4 + r;
        if (rr < N){
          float v = acc[r];
          out[(long long)rr*32 + nt*16 + m] = mul_dinv ? v*dinv[rr] : v;
        }
      }
    }
    return;
  }
  // ---- f32 fallback (legacy) ----
  int tid = threadIdx.x;
  for (int i = tid; i < 4096; i += 256) Ws[i] = ((const float*)W)[i];
  int n0 = blockIdx.x*32;
  for (int i = tid; i < 4096; i += 256){
    int r = i >> 7, k = i & 127, n = n0 + r;
    xs[i] = (n < N) ? ((const float*)x)[(long long)n*128 + k] : 0.f;
  }
  __syncthreads();
  int f = tid & 31, r = tid >> 5;
  float a0=0.f, a1=0.f, a2=0.f, a3=0.f;
  for (int k = 0; k < 128; ++k){
    float w = Ws[k*32+f];
    a0 = fmaf(xs[(r    )*128+k], w, a0);
    a1 = fmaf(xs[(r+ 8)*128+k], w, a1);
    a2 = fmaf(xs[(r+16)*128+k], w, a2);
    a3 = fmaf(xs[(r+24)*128+k], w, a3);
  }
  int n;
  n = n0+r;    if (n < N) out[n*32+f] = mul_dinv ? a0*dinv[n] : a0;
  n = n0+r+8;  if (n < N) out[n*32+f] = mul_dinv ? a1*dinv[n] : a1;
  n = n0+r+16; if (n < N) out[n*32+f] = mul_dinv ? a2*dinv[n] : a2;
  n = n0+r+24; if (n < N) out[n*32+f] = mul_dinv ? a3*dinv[n] : a3;
}

// ---------- hidden matmul: W transposed in LDS (stride 36), float4 LDS reads ----------
__global__ void k_mmh(const float* __restrict__ in, const void* __restrict__ bias, int do_relu,
                      const void* __restrict__ W, const int* __restrict__ flags,
                      const float* __restrict__ dinv, int mul_dinv,
                      float* __restrict__ out, int N){
  __shared__ float Wt[32*36];
  __shared__ float xs[32*32];
  int tid = threadIdx.x;
  int f32 = flags[0];
  for (int i = tid; i < 1024; i += 256){
    int k = i >> 5, f = i & 31;
    Wt[f*36 + k] = ldf(W, i, f32);
  }
  int n0 = blockIdx.x*32;
  for (int i = tid; i < 1024; i += 256){
    int r = i >> 5, k = i & 31, n = n0 + r;
    float v = 0.f;
    if (n < N){
      v = in[(long long)n*32+k] + ldf(bias, k, f32);
      if (do_relu) v = fmaxf(v, 0.f);
    }
    xs[i] = v;
  }
  __syncthreads();
  int f = tid & 31, r = tid >> 5;
  const float4* xs4 = (const float4*)xs;
  float a0=0.f, a1=0.f, a2=0.f, a3=0.f;
  #pragma unroll
  for (int kc = 0; kc < 8; ++kc){
    float4 wv = *(const float4*)&Wt[f*36 + kc*4];
    float4 x0 = xs4[(r    )*8 + kc];
    float4 x1 = xs4[(r+ 8)*8 + kc];
    float4 x2 = xs4[(r+16)*8 + kc];
    float4 x3 = xs4[(r+24)*8 + kc];
    a0 = fmaf(x0.x,wv.x,fmaf(x0.y,wv.y,fmaf(x0.z,wv.z,fmaf(x0.w,wv.w,a0))));
    a1 = fmaf(x1.x,wv.x,fmaf(x1.y,wv.y,fmaf(x1.z,wv.z,fmaf(x1.w,wv.w,a1))));
    a2 = fmaf(x2.x,wv.x,fmaf(x2.y,wv.y,fmaf(x2.z,wv.z,fmaf(x2.w,wv.w,a2))));
    a3 = fmaf(x3.x,wv.x,fmaf(x3.y,wv.y,fmaf(x3.z,wv.z,fmaf(x3.w,wv.w,a3))));
  }
  int n;
  n = n0+r;    if (n < N) out[n*32+f] = mul_dinv ? a0*dinv[n] : a0;
  n = n0+r+8;  if (n < N) out[n*32+f] = mul_dinv ? a1*dinv[n] : a1;
  n = n0+r+16; if (n < N) out[n*32+f] = mul_dinv ? a2*dinv[n] : a2;
  n = n0+r+24; if (n < N) out[n*32+f] = mul_dinv ? a3*dinv[n] : a3;
}

// ---------- two-phase mean pool ----------
__device__ __forceinline__ int lower_bound_i(const void* __restrict__ a, int n, int v, int i64){
  int lo = 0, hi = n;
  while (lo < hi){ int mid = (lo+hi) >> 1; if (ldi(a, mid, i64) < v) lo = mid+1; else hi = mid; }
  return lo;
}

// phase 1: 128 rows/block; running accumulator per thread, flush on graph change
__global__ void k_pool1(const float* __restrict__ agg, const void* __restrict__ batch,
                        const int* __restrict__ flags, float* __restrict__ gacc, int N){
  int i64 = flags[1];
  int f = threadIdx.x & 31, r = threadIdx.x >> 5;
  long long start = (long long)blockIdx.x*128;
  long long end = start + 128; if (end > N) end = N;
  float acc = 0.f; int curg = -1;
  for (long long n = start + r; n < end; n += 8){
    int g = ldi(batch, n, i64);
    if (g != curg){
      if (curg >= 0) atomicAdd(&gacc[curg*32 + f], acc);
      acc = 0.f; curg = g;
    }
    acc += agg[n*32 + f];
  }
  if (curg >= 0) atomicAdd(&gacc[curg*32 + f], acc);
}

// phase 2: one thread per (g,f): divide by count, add b3
__global__ void k_pool2(const float* __restrict__ gacc, const void* __restrict__ b3,
                        const void* __restrict__ batch, const int* __restrict__ flags,
                        float* __restrict__ gpool, int N, int G){
  int f32 = flags[0], i64 = flags[1];
  int idx = blockIdx.x*256 + threadIdx.x;
  if (idx < G*32){
    int g = idx >> 5, f = idx & 31;
    int s = lower_bound_i(batch, N, g, i64);
    int e = lower_bound_i(batch, N, g+1, i64);
    int c = e - s;
    gpool[idx] = (c > 0) ? gacc[idx]/(float)c + ldf(b3, f, f32) : 0.f;
  }
}

// legacy single-phase pool (fallback path)
__global__ void k_pool(const float* __restrict__ agg, const void* __restrict__ b3,
                       const void* __restrict__ batch, const int* __restrict__ flags,
                       float* __restrict__ gpool, int N){
  int f32 = flags[0], i64 = flags[1];
  int g = blockIdx.x;
  int start = lower_bound_i(batch, N, g, i64);
  int end   = lower_bound_i(batch, N, g+1, i64);
  int tid = threadIdx.x;
  int f = tid & 31, r = tid >> 5;
  float acc = 0.f;
  for (int n = start + r; n < end; n += 8) acc += agg[n*32+f];
  __shared__ float red[8][32];
  red[r][f] = acc;
  __syncthreads();
  if (r == 0){
    float s = red[0][f];
    #pragma unroll
    for (int j = 1; j < 8; ++j) s += red[j][f];
    int c = end - start;
    float gv = (c > 0) ? (s / (float)c + ldf(b3, f, f32)) : 0.f;
    gpool[g*32+f] = gv;
  }
}

// ---------- MLP head: 1 block, column-per-thread, 16 row-accumulators (ILP) ----------
__global__ void __launch_bounds__(256, 1) k_mlp(const float* __restrict__ gpool,
                      const void* __restrict__ L1w, const void* __restrict__ L1b,
                      const void* __restrict__ L2w, const void* __restrict__ L2b,
                      const void* __restrict__ L3w, const void* __restrict__ L3b,
                      const void* __restrict__ L4w, const void* __restrict__ L4b,
                      const int* __restrict__ flags, void* __restrict__ out){
  __shared__ float gin[64*32];
  __shared__ float A[64*65];
  __shared__ float B[64*65];
  __shared__ float ws[64*64];
  __shared__ float wb[64];
  int tid = threadIdx.x;
  int f32 = flags[0];
  int j  = tid & 63;
  int i0 = tid >> 6;
  float acc[16];

  for (int i = tid; i < 64*32; i += 256) gin[i] = gpool[i];
  for (int i = tid; i < 2048; i += 256) ws[i] = ldf(L1w, i, f32);
  if (tid < 64) wb[tid] = ldf(L1b, tid, f32);
  __syncthreads();
  #pragma unroll
  for (int r = 0; r < 16; ++r) acc[r] = wb[j];
  for (int k = 0; k < 32; ++k){
    float w = ws[k*64+j];
    #pragma unroll
    for (int r = 0; r < 16; ++r) acc[r] = fmaf(gin[(i0+4*r)*32+k], w, acc[r]);
  }
  #pragma unroll
  for (int r = 0; r < 16; ++r) A[(i0+4*r)*65+j] = fmaxf(acc[r], 0.f);
  __syncthreads();
  for (int i = tid; i < 4096; i += 256) ws[i] = ldf(L2w, i, f32);
  if (tid < 64) wb[tid] = ldf(L2b, tid, f32);
  __syncthreads();
  #pragma unroll
  for (int r = 0; r < 16; ++r) acc[r] = wb[j];
  for (int k = 0; k < 64; ++k){
    float w = ws[k*64+j];
    #pragma unroll
    for (int r = 0; r < 16; ++r) acc[r] = fmaf(A[(i0+4*r)*65+k], w, acc[r]);
  }
  #pragma unroll
  for (int r = 0; r < 16; ++r) B[(i0+4*r)*65+j] = fmaxf(acc[r], 0.f);
  __syncthreads();
  for (int i = tid; i < 4096; i += 256) ws[i] = ldf(L3w, i, f32);
  if (tid < 64) wb[tid] = ldf(L3b, tid, f32);
  __syncthreads();
  #pragma unroll
  for (int r = 0; r < 16; ++r) acc[r] = wb[j];
  for (int k = 0; k < 64; ++k){
    float w = ws[k*64+j];
    #pragma unroll
    for (int r = 0; r < 16; ++r) acc[r] = fmaf(B[(i0+4*r)*65+k], w, acc[r]);
  }
  #pragma unroll
  for (int r = 0; r < 16; ++r) A[(i0+4*r)*65+j] = fmaxf(acc[r], 0.f);
  __syncthreads();
  for (int i = tid; i < 640; i += 256) ws[i] = ldf(L4w, i, f32);
  if (tid < 10) wb[tid] = ldf(L4b, tid, f32);
  __syncthreads();
  if (tid < 64){
    int row = tid;
    float a10[10];
    #pragma unroll
    for (int c = 0; c < 10; ++c) a10[c] = wb[c];
    for (int k = 0; k < 64; ++k){
      float av = A[row*65+k];
      #pragma unroll
      for (int c = 0; c < 10; ++c) a10[c] = fmaf(av, ws[k*10+c], a10[c]);
    }
    #pragma unroll
    for (int c = 0; c < 10; ++c){
      if (f32) ((float*)out)[row*10+c] = a10[c];
      else     ((bf16*)out)[row*10+c]  = __float2bfloat16(a10[c]);
    }
  }
}

// ---------- fallback (atomic-scatter path, small ws) ----------
__global__ void k_init_deg(float* __restrict__ deg, int N){
  int i = blockIdx.x*256 + threadIdx.x;
  if (i < N) deg[i] = 1.0f;
}
__global__ void k_deg_accum(const void* __restrict__ eidx, long long E,
                            const void* __restrict__ w, const int* __restrict__ flags,
                            float* __restrict__ deg){
  long long e = (long long)blockIdx.x*256 + threadIdx.x;
  if (e < E){
    int f32 = flags[0], i64 = flags[1];
    atomicAdd(&deg[ldi(eidx, E + e, i64)], ldf(w, e, f32));
  }
}
__global__ void k_dinv(float* __restrict__ deg, int N){
  int i = blockIdx.x*256 + threadIdx.x;
  if (i < N){
    float d = deg[i];
    deg[i] = (d > 0.f) ? rsqrtf(fmaxf(d, 1e-30f)) : 0.f;
  }
}
__global__ void k_norm(const void* __restrict__ eidx, long long E,
                       const void* __restrict__ w, const float* __restrict__ dinv,
                       const int* __restrict__ flags, float* __restrict__ nrm){
  long long e = (long long)blockIdx.x*256 + threadIdx.x;
  if (e < E){
    int f32 = flags[0], i64 = flags[1];
    int s = ldi(eidx, e, i64), d = ldi(eidx, E + e, i64);
    nrm[e] = dinv[s] * ldf(w, e, f32) * dinv[d];
  }
}
__global__ void k_selfloop(const float* __restrict__ hlin, const float* __restrict__ dinv,
                           float* __restrict__ agg, int N){
  int idx = blockIdx.x*256 + threadIdx.x;
  if (idx < N*32){
    int n = idx >> 5;
    float di = dinv[n];
    agg[idx] = di*di*hlin[idx];
  }
}
__global__ void k_scatter(const void* __restrict__ eidx, long long E,
                          const float* __restrict__ nrm, const int* __restrict__ flags,
                          const float* __restrict__ hlin, float* __restrict__ agg){
  long long idx = (long long)blockIdx.x*256 + threadIdx.x;
  if (idx < E*32){
    int i64 = flags[1];
    long long e = idx >> 5;
    int f = (int)(idx & 31);
    int s = ldi(eidx, e, i64), d = ldi(eidx, E + e, i64);
    atomicAdd(&agg[(long long)d*32 + f], nrm[e] * hlin[(long long)s*32 + f]);
  }
}

extern "C" void kernel_launch(void* const* d_in, const int* in_sizes, int n_in,
                              void* d_out, int out_size, void* d_ws, size_t ws_size,
                              hipStream_t stream){
  const void* x   = d_in[0];
  const void* ew  = d_in[1];
  const void* W1  = d_in[2];
  const void* b1  = d_in[3];
  const void* W2  = d_in[4];
  const void* b2  = d_in[5];
  const void* W3  = d_in[6];
  const void* b3  = d_in[7];
  const void* L1w = d_in[8];  const void* L1b = d_in[9];
  const void* L2w = d_in[10]; const void* L2b = d_in[11];
  const void* L3w = d_in[12]; const void* L3b = d_in[13];
  const void* L4w = d_in[14]; const void* L4b = d_in[15];
  const void* eidx  = d_in[16];
  const void* batch = d_in[17];
  const long long E = in_sizes[1];
  const int N = in_sizes[17];
  const int G = out_size / 10;

  dim3 b(256);
  int gN   = (N + 255)/256;
  int gE   = (int)((E + 255)/256);
  int gMM  = (N + 31)/32;
  int gMM1 = (N + 63)/64;
  int gNd4 = (N + 3)/4;
  int gBH  = (int)((E + 4095)/4096);
  int gBN  = (int)((E + BINCH - 1)/BINCH);
  int gP1  = (N + 127)/128;

  const int shift = 8;                       // 256-node buckets
  int NB = (N + 255) >> 8;

  auto AL = [](size_t v){ return (v + 255) & ~(size_t)255; };

  char* base = (char*)d_ws;
  size_t off = 0;
  size_t o_flags = off; off += AL(64*4);
  size_t o_rowp  = off; off += AL((size_t)(N+1)*4);
  size_t o_dinv  = off; off += AL((size_t)N*4);
  size_t o_bbase = off; off += AL((size_t)(NB+1)*4);
  size_t o_bcnt  = off; off += AL((size_t)NB*4) + AL((size_t)NB*4) + AL((size_t)G*32*4);  // bcnt+gcur+gacc
  size_t o_csr   = off; off += AL((size_t)E*8);
  size_t o_tmp   = off; off += AL((size_t)E*8);
  size_t o_bufA  = off; off += AL((size_t)N*128);
  size_t o_bufB  = off; off += AL((size_t)N*128);
  size_t o_gp    = off; off += AL((size_t)G*32*4);
  size_t needed  = off;

  if (ws_size >= needed && NB <= 512 && N < (1<<24)){
    int*   flags  = (int*)(base + o_flags);
    int*   rowptr = (int*)(base + o_rowp);
    float* dinv   = (float*)(base + o_dinv);
    int*   bbase  = (int*)(base + o_bbase);
    int*   bcnt   = (int*)(base + o_bcnt);
    int*   gcur   = (int*)(base + o_bcnt + AL((size_t)NB*4));
    float* gacc   = (float*)(base + o_bcnt + AL((size_t)NB*4) + AL((size_t)NB*4));
    int2*  csr    = (int2*)(base + o_csr);
    int2*  csrTmp = (int2*)(base + o_tmp);
    float* bufA   = (float*)(base + o_bufA);
    float* bufB   = (float*)(base + o_bufB);
    float* gpool  = (float*)(base + o_gp);

    int nzero = (int)((AL((size_t)NB*4) + AL((size_t)NB*4))/4) + G*32;  // bcnt+gcur+gacc contiguous
    k_sniff <<<1,    b, 0, stream>>>(x, eidx, flags);
    k_zero  <<<(nzero + 255)/256, b, 0, stream>>>(bcnt, nzero);
    k_bhist <<<gBH,  b, 0, stream>>>(eidx, E, flags, shift, NB, bcnt);
    k_bscan <<<1,    b, 0, stream>>>(bcnt, bbase, NB, (int)E);
    k_bin   <<<gBN,  dim3(512), 0, stream>>>(eidx, E, ew, flags, shift, NB, bbase, gcur, csrTmp);
    k_bucket<<<NB,   dim3(1024), 0, stream>>>(csrTmp, bbase, shift, N, (int)E, csr, rowptr, dinv);
    // layer 1
    k_mm1   <<<gMM1, b, 0, stream>>>(x, W1, flags, dinv, 1, bufA, N);
    k_pull  <<<gNd4, b, 0, stream>>>(csr, rowptr, dinv, bufA, bufB, N);
    // layer 2
    k_mmh   <<<gMM,  b, 0, stream>>>(bufB, b1, 1, W2, flags, dinv, 1, bufA, N);
    k_pull  <<<gNd4, b, 0, stream>>>(csr, rowptr, dinv, bufA, bufB, N);
    // layer 3
    k_mmh   <<<gMM,  b, 0, stream>>>(bufB, b2, 1, W3, flags, dinv, 1, bufA, N);
    k_pull  <<<gNd4, b, 0, stream>>>(csr, rowptr, dinv, bufA, bufB, N);
    // head
    k_pool1<<<gP1, b, 0, stream>>>(bufB, batch, flags, gacc, N);
    k_pool2<<<(G*32 + 255)/256, b, 0, stream>>>(gacc, b3, batch, flags, gpool, N, G);
    k_mlp <<<1,  b, 0, stream>>>(gpool, L1w, L1b, L2w, L2b, L3w, L3b, L4w, L4b, flags, d_out);
    return;
  }

  // ---- fallback: atomic-scatter path ----
  {
    float* wf    = (float*)d_ws;
    int*   flags = (int*)d_ws;
    size_t Npad  = ((size_t)N + 255) & ~(size_t)255;
    float* dinv  = wf + 64;
    float* nrm   = dinv + Npad;
    float* bufA  = nrm + E;
    float* bufB  = bufA + (size_t)N*32;
    float* gpool = bufB + (size_t)N*32;
    int gN32 = (N*32 + 255)/256;
    int gE32 = (int)((E*32 + 255)/256);

    k_sniff    <<<1,    b, 0, stream>>>(x, eidx, flags);
    k_init_deg <<<gN,   b, 0, stream>>>(dinv, N);
    k_deg_accum<<<gE,   b, 0, stream>>>(eidx, E, ew, flags, dinv);
    k_dinv     <<<gN,   b, 0, stream>>>(dinv, N);
    k_norm     <<<gE,   b, 0, stream>>>(eidx, E, ew, dinv, flags, nrm);
    k_mm1      <<<gMM1, b, 0, stream>>>(x, W1, flags, dinv, 0, bufA, N);
    k_selfloop <<<gN32, b, 0, stream>>>(bufA, dinv, bufB, N);
    k_scatter  <<<gE32, b, 0, stream>>>(eidx, E, nrm, flags, bufA, bufB);
    k_mmh      <<<gMM,  b, 0, stream>>>(bufB, b1, 1, W2, flags, dinv, 0, bufA, N);
    k_selfloop <<<gN32, b, 0, stream>>>(bufA, dinv, bufB, N);
    k_scatter  <<<gE32, b, 0, stream>>>(eidx, E, nrm, flags, bufA, bufB);
    k_mmh      <<<gMM,  b, 0, stream>>>(bufB, b2, 1, W3, flags, dinv, 0, bufA, N);
    k_selfloop <<<gN32, b, 0, stream>>>(bufA, dinv, bufB, N);
    k_scatter  <<<gE32, b, 0, stream>>>(eidx, E, nrm, flags, bufA, bufB);
    k_pool<<<64, b, 0, stream>>>(bufB, b3, batch, flags, gpool, N);
    k_mlp <<<1,  b, 0, stream>>>(gpool, L1w, L1b, L2w, L2b, L3w, L3b, L4w, L4b, flags, d_out);
  }
}